// Round 1
// baseline (874.294 us; speedup 1.0000x reference)
//
#include <hip/hip_runtime.h>
#include <math.h>

#define B_    2
#define N_    2048
#define C_    768
#define H_    12
#define HD_   64
#define NROWS (B_*N_)      // 4096
#define QKVC  (3*C_)       // 2304
#define EPSV  1e-6f
#define SCALE 0.125f       // 1/sqrt(HD)

// ---------------------------------------------------------------------------
// Tiled fp32 GEMM: C[M][N] = A[M][K] @ B[K][N] + bias[N]
// 64x64 block tile, BK=16, 256 threads, 4x4 per thread (interleaved mapping).
// M%64==0, N%64==0, K%16==0 (holds for all our shapes).
// ---------------------------------------------------------------------------
__global__ __launch_bounds__(256)
void gemm_bias_kernel(const float* __restrict__ A,
                      const float* __restrict__ Bm,
                      const float* __restrict__ bias,
                      float* __restrict__ C,
                      int M, int N, int K) {
    __shared__ float As[64][17];
    __shared__ float Bs[16][68];
    const int tid = threadIdx.x;
    const int tx = tid & 15, ty = tid >> 4;
    const int mbase = blockIdx.y * 64;
    const int nbase = blockIdx.x * 64;

    float acc[4][4];
#pragma unroll
    for (int i = 0; i < 4; ++i)
#pragma unroll
        for (int j = 0; j < 4; ++j) acc[i][j] = 0.f;

    for (int k0 = 0; k0 < K; k0 += 16) {
        // stage A tile (64x16): lanes cover kk contiguously -> coalesced
        {
            const int kk = tid & 15;
            const int m0 = tid >> 4;   // 0..15
#pragma unroll
            for (int p = 0; p < 4; ++p) {
                const int m = m0 + 16 * p;
                As[m][kk] = A[(size_t)(mbase + m) * K + k0 + kk];
            }
        }
        // stage B tile (16x64): lanes cover n contiguously -> coalesced
        {
            const int n  = tid & 63;
            const int kr = tid >> 6;   // 0..3
#pragma unroll
            for (int p = 0; p < 4; ++p) {
                const int kk = kr + 4 * p;
                Bs[kk][n] = Bm[(size_t)(k0 + kk) * N + nbase + n];
            }
        }
        __syncthreads();
#pragma unroll
        for (int kk = 0; kk < 16; ++kk) {
            float a[4], b[4];
#pragma unroll
            for (int i = 0; i < 4; ++i) a[i] = As[ty + 16 * i][kk];
#pragma unroll
            for (int j = 0; j < 4; ++j) b[j] = Bs[kk][tx + 16 * j];
#pragma unroll
            for (int i = 0; i < 4; ++i)
#pragma unroll
                for (int j = 0; j < 4; ++j) acc[i][j] += a[i] * b[j];
        }
        __syncthreads();
    }

#pragma unroll
    for (int i = 0; i < 4; ++i) {
        const int m = mbase + ty + 16 * i;
#pragma unroll
        for (int j = 0; j < 4; ++j) {
            const int n = nbase + tx + 16 * j;
            C[(size_t)m * N + n] = acc[i][j] + bias[n];
        }
    }
}

// ---------------------------------------------------------------------------
// RMSNorm + RoPE, in-place on qkv buffer. One wave per (b,n,h).
// q additionally scaled by 1/sqrt(HD).
// ---------------------------------------------------------------------------
__global__ __launch_bounds__(256)
void normrope_kernel(float* __restrict__ qkv,
                     const float* __restrict__ cosb,
                     const float* __restrict__ sinb,
                     const float* __restrict__ qw,
                     const float* __restrict__ kw) {
    const int gid  = blockIdx.x * 4 + (threadIdx.x >> 6); // (b*N+n)*H + h
    const int lane = threadIdx.x & 63;
    const int h    = gid % H_;
    const int row  = gid / H_;        // b*N + n
    const int n    = row % N_;
    const size_t base = (size_t)row * QKVC + h * HD_;

    float q = qkv[base + lane];
    float k = qkv[base + C_ + lane];

    float q2 = q * q, k2 = k * k;
#pragma unroll
    for (int off = 32; off >= 1; off >>= 1) {
        q2 += __shfl_xor(q2, off, 64);
        k2 += __shfl_xor(k2, off, 64);
    }
    const float qn = q * rsqrtf(q2 * (1.f / 64.f) + EPSV) * qw[lane];
    const float kn = k * rsqrtf(k2 * (1.f / 64.f) + EPSV) * kw[lane];

    const float c = cosb[n * HD_ + lane];
    const float s = sinb[n * HD_ + lane];
    const float qp = __shfl_xor(qn, 32, 64);
    const float kp = __shfl_xor(kn, 32, 64);
    const float qrot = (lane < 32) ? -qp : qp;
    const float krot = (lane < 32) ? -kp : kp;

    qkv[base + lane]      = (qn * c + qrot * s) * SCALE;
    qkv[base + C_ + lane] =  kn * c + krot * s;
}

// ---------------------------------------------------------------------------
// Flash-style attention. One block per (b, h, 64-query tile).
// Q staged once; K/V tiles streamed. P overwrites K's LDS buffer after S
// compute so total LDS = 3*64*68*4 = 52224 B (<64 KB, 3 blocks/CU).
// q pre-scaled, so S = Qs.Ks^T directly.
// ---------------------------------------------------------------------------
__global__ __launch_bounds__(256)
void flash_kernel(const float* __restrict__ qkv,
                  float* __restrict__ attn_out) {
    __shared__ float Qs[64][68];
    __shared__ float KPs[64][68];  // K tile, then overwritten by P
    __shared__ float Vs[64][68];

    const int tid = threadIdx.x;
    const int tx = tid & 15, ty = tid >> 4;
    const int qt = blockIdx.x, h = blockIdx.y, b = blockIdx.z;
    const size_t qkvbase = (size_t)b * N_ * QKVC;

    // stage Q tile: wave covers d contiguously -> coalesced; LDS <=2-way
    {
        const int d  = tid & 63;
        const int r0 = (tid >> 6) * 16;
#pragma unroll
        for (int p = 0; p < 16; ++p) {
            const int r = r0 + p;
            Qs[r][d] = qkv[qkvbase + (size_t)(qt * 64 + r) * QKVC + h * HD_ + d];
        }
    }

    float o[4][4];
    float m_i[4], l_i[4];
#pragma unroll
    for (int i = 0; i < 4; ++i) {
        m_i[i] = -INFINITY; l_i[i] = 0.f;
#pragma unroll
        for (int j = 0; j < 4; ++j) o[i][j] = 0.f;
    }
    __syncthreads();  // Q ready; also acts as barrier A for kt=0

    for (int kt = 0; kt < 32; ++kt) {
        // stage K and V tiles
        {
            const int d  = tid & 63;
            const int r0 = (tid >> 6) * 16;
#pragma unroll
            for (int p = 0; p < 16; ++p) {
                const int r = r0 + p;
                const size_t roff =
                    qkvbase + (size_t)(kt * 64 + r) * QKVC + h * HD_ + d;
                KPs[r][d] = qkv[roff + C_];
                Vs[r][d]  = qkv[roff + 2 * C_];
            }
        }
        __syncthreads();  // barrier B: tiles staged

        // S[i][j] for rows r=ty+16i, cols c=tx+16j
        float s[4][4];
#pragma unroll
        for (int i = 0; i < 4; ++i)
#pragma unroll
            for (int j = 0; j < 4; ++j) s[i][j] = 0.f;
        for (int d = 0; d < 64; ++d) {
            float a[4], bb[4];
#pragma unroll
            for (int i = 0; i < 4; ++i) a[i]  = Qs[ty + 16 * i][d];
#pragma unroll
            for (int j = 0; j < 4; ++j) bb[j] = KPs[tx + 16 * j][d];
#pragma unroll
            for (int i = 0; i < 4; ++i)
#pragma unroll
                for (int j = 0; j < 4; ++j) s[i][j] += a[i] * bb[j];
        }
        __syncthreads();  // barrier B2: everyone done reading K

        // online softmax update; write P over K's buffer
#pragma unroll
        for (int i = 0; i < 4; ++i) {
            float mx = s[i][0];
#pragma unroll
            for (int j = 1; j < 4; ++j) mx = fmaxf(mx, s[i][j]);
#pragma unroll
            for (int off = 1; off < 16; off <<= 1)
                mx = fmaxf(mx, __shfl_xor(mx, off, 64));
            const float newm  = fmaxf(m_i[i], mx);
            const float alpha = __expf(m_i[i] - newm);
            float rsum = 0.f;
#pragma unroll
            for (int j = 0; j < 4; ++j) {
                s[i][j] = __expf(s[i][j] - newm);
                rsum += s[i][j];
            }
#pragma unroll
            for (int off = 1; off < 16; off <<= 1)
                rsum += __shfl_xor(rsum, off, 64);
            l_i[i] = l_i[i] * alpha + rsum;
            m_i[i] = newm;
#pragma unroll
            for (int j = 0; j < 4; ++j) {
                o[i][j] *= alpha;
                KPs[ty + 16 * i][tx + 16 * j] = s[i][j];
            }
        }
        __syncthreads();  // barrier C: P visible

        // O += P @ V
        for (int c = 0; c < 64; ++c) {
            float p[4], v[4];
#pragma unroll
            for (int i = 0; i < 4; ++i) p[i] = KPs[ty + 16 * i][c];
#pragma unroll
            for (int j = 0; j < 4; ++j) v[j] = Vs[c][tx + 16 * j];
#pragma unroll
            for (int i = 0; i < 4; ++i)
#pragma unroll
                for (int j = 0; j < 4; ++j) o[i][j] += p[i] * v[j];
        }
        __syncthreads();  // barrier A: safe to restage K/V/P
    }

#pragma unroll
    for (int i = 0; i < 4; ++i) {
        const int n = qt * 64 + ty + 16 * i;
        const float inv = 1.f / l_i[i];
#pragma unroll
        for (int j = 0; j < 4; ++j) {
            const int dv = tx + 16 * j;
            attn_out[((size_t)(b * N_ + n)) * C_ + h * HD_ + dv] = o[i][j] * inv;
        }
    }
}

// ---------------------------------------------------------------------------
extern "C" void kernel_launch(void* const* d_in, const int* in_sizes, int n_in,
                              void* d_out, int out_size, void* d_ws, size_t ws_size,
                              hipStream_t stream) {
    const float* x        = (const float*)d_in[0];
    const float* rope_cos = (const float*)d_in[1];
    const float* rope_sin = (const float*)d_in[2];
    const float* qkv_w    = (const float*)d_in[3];
    const float* qkv_b    = (const float*)d_in[4];
    const float* proj_w   = (const float*)d_in[5];
    const float* proj_b   = (const float*)d_in[6];
    const float* q_nw     = (const float*)d_in[7];
    const float* k_nw     = (const float*)d_in[8];
    float* out = (float*)d_out;

    // workspace: qkv [4096][2304] fp32 (37.75 MB) + attn_out [4096][768] (12.6 MB)
    float* qkv  = (float*)d_ws;
    float* attn = qkv + (size_t)NROWS * QKVC;

    // 1) qkv = x @ Wqkv + b
    gemm_bias_kernel<<<dim3(QKVC / 64, NROWS / 64), 256, 0, stream>>>(
        x, qkv_w, qkv_b, qkv, NROWS, QKVC, C_);

    // 2) RMSNorm + RoPE in place (q scaled by 1/8)
    normrope_kernel<<<dim3(B_ * N_ * H_ / 4), 256, 0, stream>>>(
        qkv, rope_cos, rope_sin, q_nw, k_nw);

    // 3) flash attention -> attn [b,n, h*64+d]
    flash_kernel<<<dim3(N_ / 64, H_, B_), 256, 0, stream>>>(qkv, attn);

    // 4) out = attn @ Wproj + b
    gemm_bias_kernel<<<dim3(C_ / 64, NROWS / 64), 256, 0, stream>>>(
        attn, proj_w, proj_b, out, NROWS, C_, C_);
}

// Round 2
// 278.433 us; speedup vs baseline: 3.1400x; 3.1400x over previous
//
#include <hip/hip_runtime.h>
#include <math.h>

#define B_    2
#define N_    2048
#define C_    768
#define H_    12
#define HD_   64
#define NROWS (B_*N_)      // 4096
#define QKVC  (3*C_)       // 2304
#define EPSV  1e-6f
#define SCALE 0.125f       // 1/sqrt(HD)

typedef unsigned short u16;
typedef short bf16x8 __attribute__((ext_vector_type(8)));   // 8 bf16 = 4 VGPRs
typedef float f32x4  __attribute__((ext_vector_type(4)));   // MFMA C/D

__device__ __forceinline__ float b2f(u16 u) {
    unsigned v = ((unsigned)u) << 16;
    return __builtin_bit_cast(float, v);
}
__device__ __forceinline__ u16 f2b(float f) {   // RNE
    unsigned u = __builtin_bit_cast(unsigned, f);
    u += 0x7fffu + ((u >> 16) & 1u);
    return (u16)(u >> 16);
}
// async global->LDS, 16B/lane; LDS dest = wave-uniform base + lane*16
__device__ __forceinline__ void gload_lds16(const void* g, void* l) {
    __builtin_amdgcn_global_load_lds(
        (const __attribute__((address_space(1))) unsigned int*)g,
        (__attribute__((address_space(3))) unsigned int*)l, 16, 0, 0);
}

// ---------------------------------------------------------------------------
// fp32 -> bf16 elementwise (n % 1024 == 0)
// ---------------------------------------------------------------------------
__global__ __launch_bounds__(256)
void cvt_bf16_kernel(const float* __restrict__ src, u16* __restrict__ dst) {
    const int i = (blockIdx.x * 256 + threadIdx.x) * 4;
    const float4 v = *(const float4*)(src + i);
    ushort4 o;
    o.x = f2b(v.x); o.y = f2b(v.y); o.z = f2b(v.z); o.w = f2b(v.w);
    *(ushort4*)(dst + i) = o;
}

// ---------------------------------------------------------------------------
// W[K][N] fp32 -> Wt[N][K] bf16 (64x64 LDS tiles, both sides coalesced)
// ---------------------------------------------------------------------------
__global__ __launch_bounds__(256)
void wtrans_kernel(const float* __restrict__ W, u16* __restrict__ Wt,
                   int K, int N) {
    __shared__ float T[64][65];
    const int k0 = blockIdx.y * 64, n0 = blockIdx.x * 64;
    const int t = threadIdx.x, r = t >> 6, c = t & 63;
#pragma unroll
    for (int p = 0; p < 16; ++p) {
        const int kl = p * 4 + r;
        T[kl][c] = W[(size_t)(k0 + kl) * N + n0 + c];
    }
    __syncthreads();
#pragma unroll
    for (int p = 0; p < 16; ++p) {
        const int nl = p * 4 + r;
        Wt[(size_t)(n0 + nl) * K + k0 + c] = f2b(T[c][nl]);
    }
}

// ---------------------------------------------------------------------------
// bf16 TN GEMM (m97 structure): C[M][N] = A[M][K] @ Bt[N][K]^T + bias
// 128x128 tile, BK=32, 256 thr / 4 waves, each wave 64x64 (4x4 16x16 blocks).
// global_load_lds width 16; LDS [row][k] pitch 32 elem (64 B) exactly.
// ---------------------------------------------------------------------------
template <bool BF16OUT>
__global__ __launch_bounds__(256)
void gemm_tn_kernel(const u16* __restrict__ A, const u16* __restrict__ Bt,
                    const float* __restrict__ bias, void* __restrict__ Cout,
                    int M, int N, int K) {
    __shared__ __attribute__((aligned(16))) u16 As[128 * 32];
    __shared__ __attribute__((aligned(16))) u16 Bs[128 * 32];
    const int tid = threadIdx.x;
    const int w = tid >> 6, l = tid & 63;
    const int lq = l & 15, quad = l >> 4;
    const int mbase = blockIdx.y * 128, nbase = blockIdx.x * 128;

    f32x4 acc[4][4];
    const f32x4 z4 = {0.f, 0.f, 0.f, 0.f};
#pragma unroll
    for (int mb = 0; mb < 4; ++mb)
#pragma unroll
        for (int nb = 0; nb < 4; ++nb) acc[mb][nb] = z4;

    // staging chunk geometry: 1 KB chunk = 16 rows x 32 bf16; wave w stages
    // chunks {2w, 2w+1} of A and of B. lane: row = 16c + (l>>2), kpart = l&3.
    const int srow = (l >> 2), kp = l & 3;

    for (int k0 = 0; k0 < K; k0 += 32) {
#pragma unroll
        for (int cc = 0; cc < 2; ++cc) {
            const int c = 2 * w + cc;
            const int row = 16 * c + srow;
            gload_lds16(A  + (size_t)(mbase + row) * K + k0 + kp * 8, &As[c * 512]);
            gload_lds16(Bt + (size_t)(nbase + row) * K + k0 + kp * 8, &Bs[c * 512]);
        }
        __syncthreads();

        bf16x8 af[4], bfr[4];
#pragma unroll
        for (int mb = 0; mb < 4; ++mb)
            af[mb] = *(const bf16x8*)&As[((w >> 1) * 64 + mb * 16 + lq) * 32 + quad * 8];
#pragma unroll
        for (int nb = 0; nb < 4; ++nb)
            bfr[nb] = *(const bf16x8*)&Bs[((w & 1) * 64 + nb * 16 + lq) * 32 + quad * 8];
#pragma unroll
        for (int mb = 0; mb < 4; ++mb)
#pragma unroll
            for (int nb = 0; nb < 4; ++nb)
                acc[mb][nb] = __builtin_amdgcn_mfma_f32_16x16x32_bf16(
                    af[mb], bfr[nb], acc[mb][nb], 0, 0, 0);
        __syncthreads();
    }

    // epilogue: C/D layout col=lane&15, row=quad*4+reg (m89-verified)
#pragma unroll
    for (int nb = 0; nb < 4; ++nb) {
        const int col = nbase + (w & 1) * 64 + nb * 16 + lq;
        const float bv = bias[col];
#pragma unroll
        for (int mb = 0; mb < 4; ++mb) {
#pragma unroll
            for (int r = 0; r < 4; ++r) {
                const int row = mbase + (w >> 1) * 64 + mb * 16 + quad * 4 + r;
                const float v = acc[mb][nb][r] + bv;
                if (BF16OUT) ((u16*)Cout)[(size_t)row * N + col] = f2b(v);
                else         ((float*)Cout)[(size_t)row * N + col] = v;
            }
        }
    }
}

// ---------------------------------------------------------------------------
// RMSNorm + RoPE in-place on bf16 qkv. One wave per (b,n,h); q scaled by 1/8.
// ---------------------------------------------------------------------------
__global__ __launch_bounds__(256)
void normrope_kernel(u16* __restrict__ qkv,
                     const float* __restrict__ cosb,
                     const float* __restrict__ sinb,
                     const float* __restrict__ qw,
                     const float* __restrict__ kw) {
    const int gid  = blockIdx.x * 4 + (threadIdx.x >> 6);
    const int lane = threadIdx.x & 63;
    const int h    = gid % H_;
    const int row  = gid / H_;
    const int n    = row % N_;
    const size_t base = (size_t)row * QKVC + h * HD_;

    float q = b2f(qkv[base + lane]);
    float k = b2f(qkv[base + C_ + lane]);

    float q2 = q * q, k2 = k * k;
#pragma unroll
    for (int off = 32; off >= 1; off >>= 1) {
        q2 += __shfl_xor(q2, off, 64);
        k2 += __shfl_xor(k2, off, 64);
    }
    const float qn = q * rsqrtf(q2 * (1.f / 64.f) + EPSV) * qw[lane];
    const float kn = k * rsqrtf(k2 * (1.f / 64.f) + EPSV) * kw[lane];

    const float c = cosb[n * HD_ + lane];
    const float s = sinb[n * HD_ + lane];
    const float qp = __shfl_xor(qn, 32, 64);
    const float kp = __shfl_xor(kn, 32, 64);
    const float qrot = (lane < 32) ? -qp : qp;
    const float krot = (lane < 32) ? -kp : kp;

    qkv[base + lane]      = f2b((qn * c + qrot * s) * SCALE);
    qkv[base + C_ + lane] = f2b(kn * c + krot * s);
}

// ---------------------------------------------------------------------------
// V transpose: qkv[b][n][1536+h*64+dv] -> vt[(b*H+h)*64+dv][n]  (bf16)
// ---------------------------------------------------------------------------
__global__ __launch_bounds__(256)
void vtrans_kernel(const u16* __restrict__ qkv, u16* __restrict__ vt) {
    __shared__ u16 T[64][65];
    const int n0 = blockIdx.x * 64, bh = blockIdx.y;
    const int b = bh / H_, h = bh % H_;
    const int t = threadIdx.x, r = t >> 6, c = t & 63;
#pragma unroll
    for (int p = 0; p < 16; ++p) {
        const int nl = p * 4 + r;
        T[nl][c] = qkv[(size_t)(b * N_ + n0 + nl) * QKVC + 2 * C_ + h * HD_ + c];
    }
    __syncthreads();
#pragma unroll
    for (int p = 0; p < 16; ++p) {
        const int dv = p * 4 + r;
        vt[((size_t)bh * HD_ + dv) * N_ + n0 + c] = T[c][dv];
    }
}

// ---------------------------------------------------------------------------
// MFMA flash attention.  Block = 128 queries of one (b,h); 4 waves x 32 q.
// S^T = K.Q^T  (A=K natural, B=Q natural; C-layout: col=query=lane&15,
// row=key=quad*4+reg).  Softmax per query = in-lane over 16 regs + shfl 16/32.
// O^T = V^T.P^T (A=Vt LDS, B=P^T read from per-wave P buffer [q][key]).
// ---------------------------------------------------------------------------
__global__ __launch_bounds__(256)
void flash_mfma_kernel(const u16* __restrict__ qkv, const u16* __restrict__ vt,
                       u16* __restrict__ attnb) {
    __shared__ __attribute__((aligned(16))) u16 Qs[128 * 64];  // [q][d]
    __shared__ __attribute__((aligned(16))) u16 Ks[64 * 64];   // [key][d]
    __shared__ __attribute__((aligned(16))) u16 Vts[64 * 64];  // [dv][key]
    __shared__ __attribute__((aligned(16))) u16 Ps[4][32 * 64];// per-wave [q][key]

    const int tid = threadIdx.x;
    const int w = tid >> 6, l = tid & 63;
    const int lq = l & 15, quad = l >> 4;
    const int qt = blockIdx.x, bh = blockIdx.y;
    const int b = bh / H_, h = bh % H_;
    const size_t qbase = (size_t)b * N_ * QKVC + h * HD_;

    // stage Q (16 KB = 16 chunks; wave w stages 4w..4w+3). row = 8c + l>>3.
    {
        const int rr = l >> 3, dp = l & 7;
#pragma unroll
        for (int cc = 0; cc < 4; ++cc) {
            const int c = 4 * w + cc;
            const int row = 8 * c + rr;
            gload_lds16(qkv + qbase + (size_t)(qt * 128 + row) * QKVC + dp * 8,
                        &Qs[c * 512]);
        }
    }
    __syncthreads();

    // hoist Q b-frags: B[k=d][n=q]: lane holds Q[w*32+nq*16+lq][ks*32+quad*8 ..+7]
    bf16x8 qb[2][2];
#pragma unroll
    for (int nq = 0; nq < 2; ++nq)
#pragma unroll
        for (int ks = 0; ks < 2; ++ks)
            qb[nq][ks] = *(const bf16x8*)&Qs[(w * 32 + nq * 16 + lq) * 64 + ks * 32 + quad * 8];

    float m_i[2] = {-INFINITY, -INFINITY};
    float l_i[2] = {0.f, 0.f};
    f32x4 oacc[4][2];
    const f32x4 z4 = {0.f, 0.f, 0.f, 0.f};
#pragma unroll
    for (int mb = 0; mb < 4; ++mb)
#pragma unroll
        for (int nq = 0; nq < 2; ++nq) oacc[mb][nq] = z4;

    const int rr = l >> 3, dp = l & 7;   // staging lane geometry

    for (int kt = 0; kt < 32; ++kt) {
        // stage K tile [key][d] and Vt tile [dv][key]; wave w: chunks 2w,2w+1
#pragma unroll
        for (int cc = 0; cc < 2; ++cc) {
            const int c = 2 * w + cc;
            const int row = 8 * c + rr;
            gload_lds16(qkv + qbase + C_ + (size_t)(kt * 64 + row) * QKVC + dp * 8,
                        &Ks[c * 512]);
            gload_lds16(vt + ((size_t)bh * HD_ + row) * N_ + kt * 64 + dp * 8,
                        &Vts[c * 512]);
        }
        __syncthreads();

        // S^T = K.Q^T
        f32x4 sacc[4][2];
#pragma unroll
        for (int kb = 0; kb < 4; ++kb)
#pragma unroll
            for (int nq = 0; nq < 2; ++nq) sacc[kb][nq] = z4;
#pragma unroll
        for (int kb = 0; kb < 4; ++kb) {
#pragma unroll
            for (int ks = 0; ks < 2; ++ks) {
                const bf16x8 ka = *(const bf16x8*)&Ks[(kb * 16 + lq) * 64 + ks * 32 + quad * 8];
#pragma unroll
                for (int nq = 0; nq < 2; ++nq)
                    sacc[kb][nq] = __builtin_amdgcn_mfma_f32_16x16x32_bf16(
                        ka, qb[nq][ks], sacc[kb][nq], 0, 0, 0);
            }
        }

        // online softmax (per lane: 1 query per nq, keys kb*16+quad*4+r)
#pragma unroll
        for (int nq = 0; nq < 2; ++nq) {
            float mx = -INFINITY;
#pragma unroll
            for (int kb = 0; kb < 4; ++kb)
#pragma unroll
                for (int r = 0; r < 4; ++r) mx = fmaxf(mx, sacc[kb][nq][r]);
            mx = fmaxf(mx, __shfl_xor(mx, 16, 64));
            mx = fmaxf(mx, __shfl_xor(mx, 32, 64));
            const float mnew  = fmaxf(m_i[nq], mx);
            const float alpha = __expf(m_i[nq] - mnew);
            float rsum = 0.f;
#pragma unroll
            for (int kb = 0; kb < 4; ++kb) {
                ushort4 pk;
#pragma unroll
                for (int r = 0; r < 4; ++r) {
                    const float p = __expf(sacc[kb][nq][r] - mnew);
                    sacc[kb][nq][r] = p;
                    rsum += p;
                    ((u16*)&pk)[r] = f2b(p);
                }
                // P[q][key]: q = nq*16+lq, keys kb*16+quad*4 .. +3  (b64 write)
                *(ushort4*)&Ps[w][(nq * 16 + lq) * 64 + kb * 16 + quad * 4] = pk;
            }
            rsum += __shfl_xor(rsum, 16, 64);
            rsum += __shfl_xor(rsum, 32, 64);
            l_i[nq] = l_i[nq] * alpha + rsum;
            m_i[nq] = mnew;
#pragma unroll
            for (int mb = 0; mb < 4; ++mb)
#pragma unroll
                for (int r = 0; r < 4; ++r) oacc[mb][nq][r] *= alpha;
        }

        // O^T += V^T.P^T   (same-wave P RAW: ordered by lgkmcnt, no barrier)
        bf16x8 pb[2][2];
#pragma unroll
        for (int ks = 0; ks < 2; ++ks)
#pragma unroll
            for (int nq = 0; nq < 2; ++nq)
                pb[ks][nq] = *(const bf16x8*)&Ps[w][(nq * 16 + lq) * 64 + ks * 32 + quad * 8];
#pragma unroll
        for (int mb = 0; mb < 4; ++mb) {
#pragma unroll
            for (int ks = 0; ks < 2; ++ks) {
                const bf16x8 va = *(const bf16x8*)&Vts[(mb * 16 + lq) * 64 + ks * 32 + quad * 8];
#pragma unroll
                for (int nq = 0; nq < 2; ++nq)
                    oacc[mb][nq] = __builtin_amdgcn_mfma_f32_16x16x32_bf16(
                        va, pb[ks][nq], oacc[mb][nq], 0, 0, 0);
            }
        }
        __syncthreads();   // protect Ks/Vts before next-tile staging
    }

    // epilogue: O^T/l -> per-wave LDS [q][dv] -> coalesced 16B stores
#pragma unroll
    for (int nq = 0; nq < 2; ++nq) {
        const float inv = 1.f / l_i[nq];
#pragma unroll
        for (int mb = 0; mb < 4; ++mb) {
            ushort4 pk;
#pragma unroll
            for (int r = 0; r < 4; ++r) ((u16*)&pk)[r] = f2b(oacc[mb][nq][r] * inv);
            *(ushort4*)&Ps[w][(nq * 16 + lq) * 64 + mb * 16 + quad * 4] = pk;
        }
    }
#pragma unroll
    for (int pass = 0; pass < 4; ++pass) {
        const int ql = pass * 8 + (l >> 3);
        const int dpp = l & 7;
        const bf16x8 v = *(const bf16x8*)&Ps[w][ql * 64 + dpp * 8];
        const int query = qt * 128 + w * 32 + ql;
        *(bf16x8*)&attnb[(size_t)(b * N_ + query) * C_ + h * HD_ + dpp * 8] = v;
    }
}

// ---------------------------------------------------------------------------
extern "C" void kernel_launch(void* const* d_in, const int* in_sizes, int n_in,
                              void* d_out, int out_size, void* d_ws, size_t ws_size,
                              hipStream_t stream) {
    const float* x        = (const float*)d_in[0];
    const float* rope_cos = (const float*)d_in[1];
    const float* rope_sin = (const float*)d_in[2];
    const float* qkv_w    = (const float*)d_in[3];
    const float* qkv_b    = (const float*)d_in[4];
    const float* proj_w   = (const float*)d_in[5];
    const float* proj_b   = (const float*)d_in[6];
    const float* q_nw     = (const float*)d_in[7];
    const float* k_nw     = (const float*)d_in[8];
    float* out = (float*)d_out;

    // ws layout (bf16 buffers), total ~42.5 MB
    u16* xb    = (u16*)d_ws;                               // 4096x768
    u16* qwt   = xb    + (size_t)NROWS * C_;               // 2304x768 (W^T)
    u16* pwt   = qwt   + (size_t)QKVC * C_;                // 768x768  (W^T)
    u16* qkvb  = pwt   + (size_t)C_ * C_;                  // 4096x2304
    u16* vtb   = qkvb  + (size_t)NROWS * QKVC;             // (B*H*64)x2048
    u16* attnb = vtb   + (size_t)B_ * H_ * HD_ * N_;       // 4096x768

    cvt_bf16_kernel<<<dim3(NROWS * C_ / 1024), 256, 0, stream>>>(x, xb);
    wtrans_kernel<<<dim3(QKVC / 64, C_ / 64), 256, 0, stream>>>(qkv_w, qwt, C_, QKVC);
    wtrans_kernel<<<dim3(C_ / 64, C_ / 64), 256, 0, stream>>>(proj_w, pwt, C_, C_);

    gemm_tn_kernel<true><<<dim3(QKVC / 128, NROWS / 128), 256, 0, stream>>>(
        xb, qwt, qkv_b, qkvb, NROWS, QKVC, C_);

    normrope_kernel<<<dim3(B_ * N_ * H_ / 4), 256, 0, stream>>>(
        qkvb, rope_cos, rope_sin, q_nw, k_nw);

    vtrans_kernel<<<dim3(N_ / 64, B_ * H_), 256, 0, stream>>>(qkvb, vtb);

    flash_mfma_kernel<<<dim3(N_ / 128, B_ * H_), 256, 0, stream>>>(qkvb, vtb, attnb);

    gemm_tn_kernel<false><<<dim3(C_ / 128, NROWS / 128), 256, 0, stream>>>(
        attnb, pwt, proj_b, out, NROWS, C_, C_);
}

// Round 3
// 248.094 us; speedup vs baseline: 3.5240x; 1.1223x over previous
//
#include <hip/hip_runtime.h>
#include <math.h>

#define B_    2
#define N_    2048
#define C_    768
#define H_    12
#define HD_   64
#define NROWS (B_*N_)      // 4096
#define QKVC  (3*C_)       // 2304
#define EPSV  1e-6f
#define SCALE 0.125f       // 1/sqrt(HD)
#define LOG2E 1.44269504088896f

typedef unsigned short u16;
typedef short bf16x8 __attribute__((ext_vector_type(8)));   // 8 bf16 = 4 VGPRs
typedef float f32x4  __attribute__((ext_vector_type(4)));   // MFMA C/D

__device__ __forceinline__ float b2f(u16 u) {
    unsigned v = ((unsigned)u) << 16;
    return __builtin_bit_cast(float, v);
}
__device__ __forceinline__ u16 f2b(float f) {   // RNE
    unsigned u = __builtin_bit_cast(unsigned, f);
    u += 0x7fffu + ((u >> 16) & 1u);
    return (u16)(u >> 16);
}
// pack two f32 -> two bf16 (lo=a, hi=b), RNE
__device__ __forceinline__ unsigned pk2(float a, float b) {
#if __has_builtin(__builtin_amdgcn_cvt_pk_bf16_f32)
    auto r = __builtin_amdgcn_cvt_pk_bf16_f32(a, b);
    return __builtin_bit_cast(unsigned, r);
#else
    return (unsigned)f2b(a) | ((unsigned)f2b(b) << 16);
#endif
}
__device__ __forceinline__ float fexp2(float x) {
#if __has_builtin(__builtin_amdgcn_exp2f)
    return __builtin_amdgcn_exp2f(x);
#else
    return exp2f(x);
#endif
}
// async global->LDS, 16B/lane; LDS dest = wave-uniform base + lane*16
__device__ __forceinline__ void gload_lds16(const void* g, void* l) {
    __builtin_amdgcn_global_load_lds(
        (const __attribute__((address_space(1))) unsigned int*)g,
        (__attribute__((address_space(3))) unsigned int*)l, 16, 0, 0);
}

// ---------------------------------------------------------------------------
// fp32 -> bf16 elementwise (n % 1024 == 0)
// ---------------------------------------------------------------------------
__global__ __launch_bounds__(256)
void cvt_bf16_kernel(const float* __restrict__ src, u16* __restrict__ dst) {
    const int i = (blockIdx.x * 256 + threadIdx.x) * 4;
    const float4 v = *(const float4*)(src + i);
    uint2 o = { pk2(v.x, v.y), pk2(v.z, v.w) };
    *(uint2*)(dst + i) = o;
}

// ---------------------------------------------------------------------------
// W[K][N] fp32 -> Wt[N][K] bf16 (64x64 LDS tiles, both sides coalesced)
// ---------------------------------------------------------------------------
__global__ __launch_bounds__(256)
void wtrans_kernel(const float* __restrict__ W, u16* __restrict__ Wt,
                   int K, int N) {
    __shared__ float T[64][65];
    const int k0 = blockIdx.y * 64, n0 = blockIdx.x * 64;
    const int t = threadIdx.x, r = t >> 6, c = t & 63;
#pragma unroll
    for (int p = 0; p < 16; ++p) {
        const int kl = p * 4 + r;
        T[kl][c] = W[(size_t)(k0 + kl) * N + n0 + c];
    }
    __syncthreads();
#pragma unroll
    for (int p = 0; p < 16; ++p) {
        const int nl = p * 4 + r;
        Wt[(size_t)(n0 + nl) * K + k0 + c] = f2b(T[c][nl]);
    }
}

// ---------------------------------------------------------------------------
// bf16 TN GEMM: C[M][N] = A[M][K] @ Bt[N][K]^T + bias
// 128x128 tile, BK=32, 256 thr / 4 waves. LDS pitch 32 elem, 16B-chunk XOR
// swizzle (chunk ^= row&3) staged by inverting the swizzle on global addrs.
// ---------------------------------------------------------------------------
template <bool BF16OUT>
__global__ __launch_bounds__(256)
void gemm_tn_kernel(const u16* __restrict__ A, const u16* __restrict__ Bt,
                    const float* __restrict__ bias, void* __restrict__ Cout,
                    int M, int N, int K) {
    __shared__ __attribute__((aligned(16))) u16 As[128 * 32];
    __shared__ __attribute__((aligned(16))) u16 Bs[128 * 32];
    const int tid = threadIdx.x;
    const int w = tid >> 6, l = tid & 63;
    const int lq = l & 15, quad = l >> 4;
    const int mbase = blockIdx.y * 128, nbase = blockIdx.x * 128;

    f32x4 acc[4][4];
    const f32x4 z4 = {0.f, 0.f, 0.f, 0.f};
#pragma unroll
    for (int mb = 0; mb < 4; ++mb)
#pragma unroll
        for (int nb = 0; nb < 4; ++nb) acc[mb][nb] = z4;

    // staging: 1 KB chunk = 16 rows x 32 bf16; wave w stages chunks {2w,2w+1}.
    // lane: row = 16c + (l>>2), LDS slot (l&3); global k-chunk = (l&3)^(row&3).
    const int srow = (l >> 2);
    const int sdc  = (l & 3) ^ ((l >> 2) & 3);

    for (int k0 = 0; k0 < K; k0 += 32) {
#pragma unroll
        for (int cc = 0; cc < 2; ++cc) {
            const int c = 2 * w + cc;
            const int row = 16 * c + srow;
            gload_lds16(A  + (size_t)(mbase + row) * K + k0 + sdc * 8, &As[c * 512]);
            gload_lds16(Bt + (size_t)(nbase + row) * K + k0 + sdc * 8, &Bs[c * 512]);
        }
        __syncthreads();

        bf16x8 af[4], bfr[4];
#pragma unroll
        for (int mb = 0; mb < 4; ++mb)
            af[mb] = *(const bf16x8*)
                &As[((w >> 1) * 64 + mb * 16 + lq) * 32 + ((quad ^ (lq & 3)) * 8)];
#pragma unroll
        for (int nb = 0; nb < 4; ++nb)
            bfr[nb] = *(const bf16x8*)
                &Bs[((w & 1) * 64 + nb * 16 + lq) * 32 + ((quad ^ (lq & 3)) * 8)];
#pragma unroll
        for (int mb = 0; mb < 4; ++mb)
#pragma unroll
            for (int nb = 0; nb < 4; ++nb)
                acc[mb][nb] = __builtin_amdgcn_mfma_f32_16x16x32_bf16(
                    af[mb], bfr[nb], acc[mb][nb], 0, 0, 0);
        __syncthreads();
    }

    // epilogue: C/D layout col=lane&15, row=quad*4+reg (m89-verified)
#pragma unroll
    for (int nb = 0; nb < 4; ++nb) {
        const int col = nbase + (w & 1) * 64 + nb * 16 + lq;
        const float bv = bias[col];
#pragma unroll
        for (int mb = 0; mb < 4; ++mb) {
#pragma unroll
            for (int r = 0; r < 4; ++r) {
                const int row = mbase + (w >> 1) * 64 + mb * 16 + quad * 4 + r;
                const float v = acc[mb][nb][r] + bv;
                if (BF16OUT) ((u16*)Cout)[(size_t)row * N + col] = f2b(v);
                else         ((float*)Cout)[(size_t)row * N + col] = v;
            }
        }
    }
}

// ---------------------------------------------------------------------------
// RMSNorm + RoPE in-place on bf16 qkv, vectorized: 16 lanes per (row,h),
// ushort4 per lane. q scaled by SCALE*log2e (exp2-domain softmax downstream).
// ---------------------------------------------------------------------------
__global__ __launch_bounds__(256)
void normrope_kernel(u16* __restrict__ qkv,
                     const float* __restrict__ cosb,
                     const float* __restrict__ sinb,
                     const float* __restrict__ qw,
                     const float* __restrict__ kw) {
    const int item = blockIdx.x * 16 + (threadIdx.x >> 4); // (b*N+n)*H + h
    const int lq   = threadIdx.x & 15;
    const int h    = item % H_;
    const int row  = item / H_;
    const int n    = row % N_;
    const size_t base = (size_t)row * QKVC + h * HD_ + lq * 4;

    const ushort4 q4 = *(const ushort4*)&qkv[base];
    const ushort4 k4 = *(const ushort4*)&qkv[base + C_];
    float qf[4], kf[4];
    qf[0] = b2f(q4.x); qf[1] = b2f(q4.y); qf[2] = b2f(q4.z); qf[3] = b2f(q4.w);
    kf[0] = b2f(k4.x); kf[1] = b2f(k4.y); kf[2] = b2f(k4.z); kf[3] = b2f(k4.w);

    float q2 = qf[0]*qf[0] + qf[1]*qf[1] + qf[2]*qf[2] + qf[3]*qf[3];
    float k2 = kf[0]*kf[0] + kf[1]*kf[1] + kf[2]*kf[2] + kf[3]*kf[3];
#pragma unroll
    for (int off = 8; off >= 1; off >>= 1) {   // reduce within 16-lane group
        q2 += __shfl_xor(q2, off, 64);
        k2 += __shfl_xor(k2, off, 64);
    }
    const float rq = rsqrtf(q2 * (1.f / 64.f) + EPSV);
    const float rk = rsqrtf(k2 * (1.f / 64.f) + EPSV);

    const float4 qwv = *(const float4*)&qw[lq * 4];
    const float4 kwv = *(const float4*)&kw[lq * 4];
    const float4 cv  = *(const float4*)&cosb[n * HD_ + lq * 4];
    const float4 sv  = *(const float4*)&sinb[n * HD_ + lq * 4];

    float qn[4], kn[4];
    qn[0] = qf[0]*rq*qwv.x; qn[1] = qf[1]*rq*qwv.y;
    qn[2] = qf[2]*rq*qwv.z; qn[3] = qf[3]*rq*qwv.w;
    kn[0] = kf[0]*rk*kwv.x; kn[1] = kf[1]*rk*kwv.y;
    kn[2] = kf[2]*rk*kwv.z; kn[3] = kf[3]*rk*kwv.w;

    const float sgn = (lq < 8) ? -1.f : 1.f;   // partner lane = lq^8 (d +/- 32)
    float qo[4], ko[4];
    const float cc[4] = {cv.x, cv.y, cv.z, cv.w};
    const float ss[4] = {sv.x, sv.y, sv.z, sv.w};
#pragma unroll
    for (int j = 0; j < 4; ++j) {
        const float qp = __shfl_xor(qn[j], 8, 64);
        const float kp = __shfl_xor(kn[j], 8, 64);
        qo[j] = (qn[j] * cc[j] + sgn * qp * ss[j]) * (SCALE * LOG2E);
        ko[j] =  kn[j] * cc[j] + sgn * kp * ss[j];
    }
    uint2 qout = { pk2(qo[0], qo[1]), pk2(qo[2], qo[3]) };
    uint2 kout = { pk2(ko[0], ko[1]), pk2(ko[2], ko[3]) };
    *(uint2*)&qkv[base]      = qout;
    *(uint2*)&qkv[base + C_] = kout;
}

// ---------------------------------------------------------------------------
// V transpose: qkv[b][n][1536+h*64+dv] -> vt[(b*H+h)*64+dv][n]  (bf16)
// ---------------------------------------------------------------------------
__global__ __launch_bounds__(256)
void vtrans_kernel(const u16* __restrict__ qkv, u16* __restrict__ vt) {
    __shared__ u16 T[64][65];
    const int n0 = blockIdx.x * 64, bh = blockIdx.y;
    const int b = bh / H_, h = bh % H_;
    const int t = threadIdx.x, r = t >> 6, c = t & 63;
#pragma unroll
    for (int p = 0; p < 16; ++p) {
        const int nl = p * 4 + r;
        T[nl][c] = qkv[(size_t)(b * N_ + n0 + nl) * QKVC + 2 * C_ + h * HD_ + c];
    }
    __syncthreads();
#pragma unroll
    for (int p = 0; p < 16; ++p) {
        const int dv = p * 4 + r;
        vt[((size_t)bh * HD_ + dv) * N_ + n0 + c] = T[c][dv];
    }
}

// ---------------------------------------------------------------------------
// Barrier-free MFMA flash attention.
// Block = 128 thr = 2 waves; each wave owns 32 queries (nq=2) of a 64-q tile.
// Grid = 768 (exactly 3 blocks/CU). Q/K/V fragments loaded DIRECTLY from
// global (16B/lane, L2-resident via XCD-pinned bh mapping). Only LDS use is
// the per-wave P / O layout transform, XOR-swizzled (2-way max = free).
// No __syncthreads anywhere. Softmax in exp2 domain (q pre-scaled by log2e).
// ---------------------------------------------------------------------------
__global__ __launch_bounds__(128)
void flash_mfma_kernel(const u16* __restrict__ qkv, const u16* __restrict__ vt,
                       u16* __restrict__ attnb) {
    __shared__ __attribute__((aligned(16))) u16 Ps[2][32 * 64]; // per-wave [q][key]

    const int tid = threadIdx.x;
    const int w = tid >> 6, l = tid & 63;
    const int lq = l & 15, quad = l >> 4;
    const int sw = lq & 7;                 // row-swizzle key (q row = ..+lq)

    // XCD-pinned block remap: xcd = lin&7 handles bh {3x..3x+2} (same b),
    // keeping K/V/Q working set (~2.3 MB) inside one XCD's 4 MB L2.
    const int lin  = blockIdx.x;
    const int slot = lin >> 3;                      // 0..95
    const int bh   = (lin & 7) * 3 + (slot >> 5);   // 0..23
    const int qt   = slot & 31;                     // 64-query tile
    const int b = bh / H_, h = bh % H_;
    const size_t qbase = (size_t)b * N_ * QKVC + h * HD_;

    // Q B-frags direct from global: B[k=d][n=q], lane = Q[q=nq*16+lq][quad*8+j]
    bf16x8 qb[2][2];
#pragma unroll
    for (int nq = 0; nq < 2; ++nq)
#pragma unroll
        for (int ks = 0; ks < 2; ++ks)
            qb[nq][ks] = *(const bf16x8*)
                &qkv[qbase + (size_t)(qt * 64 + w * 32 + nq * 16 + lq) * QKVC
                     + ks * 32 + quad * 8];

    float m_i[2] = {-INFINITY, -INFINITY};
    float l_i[2] = {0.f, 0.f};
    f32x4 oacc[4][2];
    const f32x4 z4 = {0.f, 0.f, 0.f, 0.f};
#pragma unroll
    for (int mb = 0; mb < 4; ++mb)
#pragma unroll
        for (int nq = 0; nq < 2; ++nq) oacc[mb][nq] = z4;

    for (int kt = 0; kt < 32; ++kt) {
        // S^T = K.Q^T ; K A-frags direct from global
        f32x4 sacc[4][2];
#pragma unroll
        for (int kb = 0; kb < 4; ++kb)
#pragma unroll
            for (int nq = 0; nq < 2; ++nq) sacc[kb][nq] = z4;
#pragma unroll
        for (int kb = 0; kb < 4; ++kb) {
#pragma unroll
            for (int ks = 0; ks < 2; ++ks) {
                const bf16x8 ka = *(const bf16x8*)
                    &qkv[qbase + C_ + (size_t)(kt * 64 + kb * 16 + lq) * QKVC
                         + ks * 32 + quad * 8];
#pragma unroll
                for (int nq = 0; nq < 2; ++nq)
                    sacc[kb][nq] = __builtin_amdgcn_mfma_f32_16x16x32_bf16(
                        ka, qb[nq][ks], sacc[kb][nq], 0, 0, 0);
            }
        }

        // online softmax (exp2 domain); write P to per-wave swizzled LDS
#pragma unroll
        for (int nq = 0; nq < 2; ++nq) {
            const int qrow = nq * 16 + lq;
            float mx = -INFINITY;
#pragma unroll
            for (int kb = 0; kb < 4; ++kb)
#pragma unroll
                for (int r = 0; r < 4; ++r) mx = fmaxf(mx, sacc[kb][nq][r]);
            mx = fmaxf(mx, __shfl_xor(mx, 16, 64));
            mx = fmaxf(mx, __shfl_xor(mx, 32, 64));
            const float mnew  = fmaxf(m_i[nq], mx);
            const float alpha = fexp2(m_i[nq] - mnew);
            float rsum = 0.f;
#pragma unroll
            for (int kb = 0; kb < 4; ++kb) {
                float p[4];
#pragma unroll
                for (int r = 0; r < 4; ++r) {
                    p[r] = fexp2(sacc[kb][nq][r] - mnew);
                    rsum += p[r];
                }
                // keys kb*16+quad*4..+3 : chunk16 = kb*2+(quad>>1), half=quad&1
                uint2 pkv = { pk2(p[0], p[1]), pk2(p[2], p[3]) };
                *(uint2*)&Ps[w][qrow * 64
                                + (((kb * 2 + (quad >> 1)) ^ sw) * 8)
                                + (quad & 1) * 4] = pkv;
            }
            rsum += __shfl_xor(rsum, 16, 64);
            rsum += __shfl_xor(rsum, 32, 64);
            l_i[nq] = l_i[nq] * alpha + rsum;
            m_i[nq] = mnew;
#pragma unroll
            for (int mb = 0; mb < 4; ++mb)
#pragma unroll
                for (int r = 0; r < 4; ++r) oacc[mb][nq][r] *= alpha;
        }

        // O^T += V^T.P^T ; V A-frags direct from global; P B-frags from LDS
        // (same-wave LDS RAW — in-order DS pipe, compiler lgkmcnt; no barrier)
        bf16x8 pb[2][2];
#pragma unroll
        for (int ks = 0; ks < 2; ++ks)
#pragma unroll
            for (int nq = 0; nq < 2; ++nq)
                pb[ks][nq] = *(const bf16x8*)
                    &Ps[w][(nq * 16 + lq) * 64 + (((ks * 4 + quad) ^ sw) * 8)];
#pragma unroll
        for (int mb = 0; mb < 4; ++mb) {
#pragma unroll
            for (int ks = 0; ks < 2; ++ks) {
                const bf16x8 va = *(const bf16x8*)
                    &vt[((size_t)bh * HD_ + mb * 16 + lq) * N_
                        + kt * 64 + ks * 32 + quad * 8];
#pragma unroll
                for (int nq = 0; nq < 2; ++nq)
                    oacc[mb][nq] = __builtin_amdgcn_mfma_f32_16x16x32_bf16(
                        va, pb[ks][nq], oacc[mb][nq], 0, 0, 0);
            }
        }
    }

    // epilogue: O^T/l -> per-wave swizzled LDS [q][dv] -> coalesced 16B stores
#pragma unroll
    for (int nq = 0; nq < 2; ++nq) {
        const int qrow = nq * 16 + lq;
        const float inv = 1.f / l_i[nq];
#pragma unroll
        for (int mb = 0; mb < 4; ++mb) {
            uint2 ov = { pk2(oacc[mb][nq][0] * inv, oacc[mb][nq][1] * inv),
                         pk2(oacc[mb][nq][2] * inv, oacc[mb][nq][3] * inv) };
            *(uint2*)&Ps[w][qrow * 64
                            + (((mb * 2 + (quad >> 1)) ^ sw) * 8)
                            + (quad & 1) * 4] = ov;
        }
    }
#pragma unroll
    for (int pass = 0; pass < 4; ++pass) {
        const int ql = pass * 8 + (l >> 3);          // q_local 0..31
        const int c  = l & 7;                        // global dv chunk
        const bf16x8 v = *(const bf16x8*)&Ps[w][ql * 64 + ((c ^ (ql & 7)) * 8)];
        const int query = qt * 64 + w * 32 + ql;
        *(bf16x8*)&attnb[(size_t)(b * N_ + query) * C_ + h * HD_ + c * 8] = v;
    }
}

// ---------------------------------------------------------------------------
extern "C" void kernel_launch(void* const* d_in, const int* in_sizes, int n_in,
                              void* d_out, int out_size, void* d_ws, size_t ws_size,
                              hipStream_t stream) {
    const float* x        = (const float*)d_in[0];
    const float* rope_cos = (const float*)d_in[1];
    const float* rope_sin = (const float*)d_in[2];
    const float* qkv_w    = (const float*)d_in[3];
    const float* qkv_b    = (const float*)d_in[4];
    const float* proj_w   = (const float*)d_in[5];
    const float* proj_b   = (const float*)d_in[6];
    const float* q_nw     = (const float*)d_in[7];
    const float* k_nw     = (const float*)d_in[8];
    float* out = (float*)d_out;

    // ws layout (bf16 buffers), total ~42.5 MB
    u16* xb    = (u16*)d_ws;                               // 4096x768
    u16* qwt   = xb    + (size_t)NROWS * C_;               // 2304x768 (W^T)
    u16* pwt   = qwt   + (size_t)QKVC * C_;                // 768x768  (W^T)
    u16* qkvb  = pwt   + (size_t)C_ * C_;                  // 4096x2304
    u16* vtb   = qkvb  + (size_t)NROWS * QKVC;             // (B*H*64)x2048
    u16* attnb = vtb   + (size_t)B_ * H_ * HD_ * N_;       // 4096x768

    cvt_bf16_kernel<<<dim3(NROWS * C_ / 1024), 256, 0, stream>>>(x, xb);
    wtrans_kernel<<<dim3(QKVC / 64, C_ / 64), 256, 0, stream>>>(qkv_w, qwt, C_, QKVC);
    wtrans_kernel<<<dim3(C_ / 64, C_ / 64), 256, 0, stream>>>(proj_w, pwt, C_, C_);

    gemm_tn_kernel<true><<<dim3(QKVC / 128, NROWS / 128), 256, 0, stream>>>(
        xb, qwt, qkv_b, qkvb, NROWS, QKVC, C_);

    normrope_kernel<<<dim3(NROWS * H_ / 16), 256, 0, stream>>>(
        qkvb, rope_cos, rope_sin, q_nw, k_nw);

    vtrans_kernel<<<dim3(N_ / 64, B_ * H_), 256, 0, stream>>>(qkvb, vtb);

    flash_mfma_kernel<<<dim3(32 * B_ * H_), 128, 0, stream>>>(qkvb, vtb, attnb);

    gemm_tn_kernel<false><<<dim3(C_ / 128, NROWS / 128), 256, 0, stream>>>(
        attnb, pwt, proj_b, out, NROWS, C_, C_);
}

// Round 4
// 240.246 us; speedup vs baseline: 3.6392x; 1.0327x over previous
//
#include <hip/hip_runtime.h>
#include <math.h>

#define B_    2
#define N_    2048
#define C_    768
#define H_    12
#define HD_   64
#define NROWS (B_*N_)      // 4096
#define QKVC  (3*C_)       // 2304
#define EPSV  1e-6f
#define SCALE 0.125f       // 1/sqrt(HD)
#define LOG2E 1.44269504088896f
#define SMAX  12.0f        // static softmax max: logit*log2e <= 8*1.443+bf16 eps < 12

typedef unsigned short u16;
typedef short bf16x8 __attribute__((ext_vector_type(8)));   // 8 bf16 = 4 VGPRs
typedef float f32x4  __attribute__((ext_vector_type(4)));   // MFMA C/D

__device__ __forceinline__ float b2f(u16 u) {
    unsigned v = ((unsigned)u) << 16;
    return __builtin_bit_cast(float, v);
}
__device__ __forceinline__ u16 f2b(float f) {   // RNE
    unsigned u = __builtin_bit_cast(unsigned, f);
    u += 0x7fffu + ((u >> 16) & 1u);
    return (u16)(u >> 16);
}
// pack two f32 -> two bf16 (lo=a, hi=b), RNE
__device__ __forceinline__ unsigned pk2(float a, float b) {
#if __has_builtin(__builtin_amdgcn_cvt_pk_bf16_f32)
    auto r = __builtin_amdgcn_cvt_pk_bf16_f32(a, b);
    return __builtin_bit_cast(unsigned, r);
#else
    return (unsigned)f2b(a) | ((unsigned)f2b(b) << 16);
#endif
}
__device__ __forceinline__ float fexp2(float x) {
#if __has_builtin(__builtin_amdgcn_exp2f)
    return __builtin_amdgcn_exp2f(x);
#else
    return exp2f(x);
#endif
}
// async global->LDS, 16B/lane; LDS dest = wave-uniform base + lane*16
__device__ __forceinline__ void gload_lds16(const void* g, void* l) {
    __builtin_amdgcn_global_load_lds(
        (const __attribute__((address_space(1))) unsigned int*)g,
        (__attribute__((address_space(3))) unsigned int*)l, 16, 0, 0);
}

// ---------------------------------------------------------------------------
// fp32 -> bf16 elementwise (n % 1024 == 0)
// ---------------------------------------------------------------------------
__global__ __launch_bounds__(256)
void cvt_bf16_kernel(const float* __restrict__ src, u16* __restrict__ dst) {
    const int i = (blockIdx.x * 256 + threadIdx.x) * 4;
    const float4 v = *(const float4*)(src + i);
    uint2 o = { pk2(v.x, v.y), pk2(v.z, v.w) };
    *(uint2*)(dst + i) = o;
}

// ---------------------------------------------------------------------------
// W[K][N] fp32 -> Wt[N][K] bf16 (64x64 LDS tiles, both sides coalesced)
// ---------------------------------------------------------------------------
__global__ __launch_bounds__(256)
void wtrans_kernel(const float* __restrict__ W, u16* __restrict__ Wt,
                   int K, int N) {
    __shared__ float T[64][65];
    const int k0 = blockIdx.y * 64, n0 = blockIdx.x * 64;
    const int t = threadIdx.x, r = t >> 6, c = t & 63;
#pragma unroll
    for (int p = 0; p < 16; ++p) {
        const int kl = p * 4 + r;
        T[kl][c] = W[(size_t)(k0 + kl) * N + n0 + c];
    }
    __syncthreads();
#pragma unroll
    for (int p = 0; p < 16; ++p) {
        const int nl = p * 4 + r;
        Wt[(size_t)(n0 + nl) * K + k0 + c] = f2b(T[c][nl]);
    }
}

// ---------------------------------------------------------------------------
// bf16 TN GEMM: C[M][N] = A[M][K] @ Bt[N][K]^T + bias
// 128x128 tile, BK=32, 256 thr / 4 waves. LDS pitch 32 elem, 16B-chunk XOR
// swizzle (chunk ^= row&3) staged by inverting the swizzle on global addrs.
// ---------------------------------------------------------------------------
template <bool BF16OUT>
__global__ __launch_bounds__(256)
void gemm_tn_kernel(const u16* __restrict__ A, const u16* __restrict__ Bt,
                    const float* __restrict__ bias, void* __restrict__ Cout,
                    int M, int N, int K) {
    __shared__ __attribute__((aligned(16))) u16 As[128 * 32];
    __shared__ __attribute__((aligned(16))) u16 Bs[128 * 32];
    const int tid = threadIdx.x;
    const int w = tid >> 6, l = tid & 63;
    const int lq = l & 15, quad = l >> 4;
    const int mbase = blockIdx.y * 128, nbase = blockIdx.x * 128;

    f32x4 acc[4][4];
    const f32x4 z4 = {0.f, 0.f, 0.f, 0.f};
#pragma unroll
    for (int mb = 0; mb < 4; ++mb)
#pragma unroll
        for (int nb = 0; nb < 4; ++nb) acc[mb][nb] = z4;

    // staging: 1 KB chunk = 16 rows x 32 bf16; wave w stages chunks {2w,2w+1}.
    // lane: row = 16c + (l>>2), LDS slot (l&3); global k-chunk = (l&3)^(row&3).
    const int srow = (l >> 2);
    const int sdc  = (l & 3) ^ ((l >> 2) & 3);

    for (int k0 = 0; k0 < K; k0 += 32) {
#pragma unroll
        for (int cc = 0; cc < 2; ++cc) {
            const int c = 2 * w + cc;
            const int row = 16 * c + srow;
            gload_lds16(A  + (size_t)(mbase + row) * K + k0 + sdc * 8, &As[c * 512]);
            gload_lds16(Bt + (size_t)(nbase + row) * K + k0 + sdc * 8, &Bs[c * 512]);
        }
        __syncthreads();

        bf16x8 af[4], bfr[4];
#pragma unroll
        for (int mb = 0; mb < 4; ++mb)
            af[mb] = *(const bf16x8*)
                &As[((w >> 1) * 64 + mb * 16 + lq) * 32 + ((quad ^ (lq & 3)) * 8)];
#pragma unroll
        for (int nb = 0; nb < 4; ++nb)
            bfr[nb] = *(const bf16x8*)
                &Bs[((w & 1) * 64 + nb * 16 + lq) * 32 + ((quad ^ (lq & 3)) * 8)];
#pragma unroll
        for (int mb = 0; mb < 4; ++mb)
#pragma unroll
            for (int nb = 0; nb < 4; ++nb)
                acc[mb][nb] = __builtin_amdgcn_mfma_f32_16x16x32_bf16(
                    af[mb], bfr[nb], acc[mb][nb], 0, 0, 0);
        __syncthreads();
    }

    // epilogue: C/D layout col=lane&15, row=quad*4+reg (m89-verified)
#pragma unroll
    for (int nb = 0; nb < 4; ++nb) {
        const int col = nbase + (w & 1) * 64 + nb * 16 + lq;
        const float bv = bias[col];
#pragma unroll
        for (int mb = 0; mb < 4; ++mb) {
#pragma unroll
            for (int r = 0; r < 4; ++r) {
                const int row = mbase + (w >> 1) * 64 + mb * 16 + quad * 4 + r;
                const float v = acc[mb][nb][r] + bv;
                if (BF16OUT) ((u16*)Cout)[(size_t)row * N + col] = f2b(v);
                else         ((float*)Cout)[(size_t)row * N + col] = v;
            }
        }
    }
}

// ---------------------------------------------------------------------------
// RMSNorm + RoPE in-place on bf16 qkv, vectorized: 16 lanes per (row,h),
// ushort4 per lane. q scaled by SCALE*log2e (exp2-domain softmax downstream).
// ---------------------------------------------------------------------------
__global__ __launch_bounds__(256)
void normrope_kernel(u16* __restrict__ qkv,
                     const float* __restrict__ cosb,
                     const float* __restrict__ sinb,
                     const float* __restrict__ qw,
                     const float* __restrict__ kw) {
    const int item = blockIdx.x * 16 + (threadIdx.x >> 4); // (b*N+n)*H + h
    const int lq   = threadIdx.x & 15;
    const int h    = item % H_;
    const int row  = item / H_;
    const int n    = row % N_;
    const size_t base = (size_t)row * QKVC + h * HD_ + lq * 4;

    const ushort4 q4 = *(const ushort4*)&qkv[base];
    const ushort4 k4 = *(const ushort4*)&qkv[base + C_];
    float qf[4], kf[4];
    qf[0] = b2f(q4.x); qf[1] = b2f(q4.y); qf[2] = b2f(q4.z); qf[3] = b2f(q4.w);
    kf[0] = b2f(k4.x); kf[1] = b2f(k4.y); kf[2] = b2f(k4.z); kf[3] = b2f(k4.w);

    float q2 = qf[0]*qf[0] + qf[1]*qf[1] + qf[2]*qf[2] + qf[3]*qf[3];
    float k2 = kf[0]*kf[0] + kf[1]*kf[1] + kf[2]*kf[2] + kf[3]*kf[3];
#pragma unroll
    for (int off = 8; off >= 1; off >>= 1) {   // reduce within 16-lane group
        q2 += __shfl_xor(q2, off, 64);
        k2 += __shfl_xor(k2, off, 64);
    }
    const float rq = rsqrtf(q2 * (1.f / 64.f) + EPSV);
    const float rk = rsqrtf(k2 * (1.f / 64.f) + EPSV);

    const float4 qwv = *(const float4*)&qw[lq * 4];
    const float4 kwv = *(const float4*)&kw[lq * 4];
    const float4 cv  = *(const float4*)&cosb[n * HD_ + lq * 4];
    const float4 sv  = *(const float4*)&sinb[n * HD_ + lq * 4];

    float qn[4], kn[4];
    qn[0] = qf[0]*rq*qwv.x; qn[1] = qf[1]*rq*qwv.y;
    qn[2] = qf[2]*rq*qwv.z; qn[3] = qf[3]*rq*qwv.w;
    kn[0] = kf[0]*rk*kwv.x; kn[1] = kf[1]*rk*kwv.y;
    kn[2] = kf[2]*rk*kwv.z; kn[3] = kf[3]*rk*kwv.w;

    const float sgn = (lq < 8) ? -1.f : 1.f;   // partner lane = lq^8 (d +/- 32)
    float qo[4], ko[4];
    const float cc[4] = {cv.x, cv.y, cv.z, cv.w};
    const float ss[4] = {sv.x, sv.y, sv.z, sv.w};
#pragma unroll
    for (int j = 0; j < 4; ++j) {
        const float qp = __shfl_xor(qn[j], 8, 64);
        const float kp = __shfl_xor(kn[j], 8, 64);
        qo[j] = (qn[j] * cc[j] + sgn * qp * ss[j]) * (SCALE * LOG2E);
        ko[j] =  kn[j] * cc[j] + sgn * kp * ss[j];
    }
    uint2 qout = { pk2(qo[0], qo[1]), pk2(qo[2], qo[3]) };
    uint2 kout = { pk2(ko[0], ko[1]), pk2(ko[2], ko[3]) };
    *(uint2*)&qkv[base]      = qout;
    *(uint2*)&qkv[base + C_] = kout;
}

// ---------------------------------------------------------------------------
// V transpose: qkv[b][n][1536+h*64+dv] -> vt[(b*H+h)*64+dv][n]  (bf16)
// ---------------------------------------------------------------------------
__global__ __launch_bounds__(256)
void vtrans_kernel(const u16* __restrict__ qkv, u16* __restrict__ vt) {
    __shared__ u16 T[64][65];
    const int n0 = blockIdx.x * 64, bh = blockIdx.y;
    const int b = bh / H_, h = bh % H_;
    const int t = threadIdx.x, r = t >> 6, c = t & 63;
#pragma unroll
    for (int p = 0; p < 16; ++p) {
        const int nl = p * 4 + r;
        T[nl][c] = qkv[(size_t)(b * N_ + n0 + nl) * QKVC + 2 * C_ + h * HD_ + c];
    }
    __syncthreads();
#pragma unroll
    for (int p = 0; p < 16; ++p) {
        const int dv = p * 4 + r;
        vt[((size_t)bh * HD_ + dv) * N_ + n0 + c] = T[c][dv];
    }
}

// ---------------------------------------------------------------------------
// MFMA flash attention, K-split-in-block + static-max softmax + prefetch.
// Block = 128 thr = 2 waves over the SAME 32 queries; wave w handles keys
// kt = 2*kt2+w (16 tiles each). Static max (SMAX) makes partials additive:
// one LDS exchange + one __syncthreads at the end combines the halves.
// K frags prefetched in-place for t+1 right after S-MFMAs consume them;
// V frags issued at iteration top (used ~500 cyc later). No max reduce,
// no alpha rescale. Grid = 1536 (8 waves/CU at launch_bounds(128,2)).
// ---------------------------------------------------------------------------
__global__ __launch_bounds__(128, 2)
void flash_mfma_kernel(const u16* __restrict__ qkv, const u16* __restrict__ vt,
                       u16* __restrict__ attnb) {
    __shared__ __attribute__((aligned(16))) u16 Ps[2][32 * 64]; // per-wave [q][key]
    __shared__ __attribute__((aligned(16))) float Oex[32 * 64]; // exchange [q][dv]
    __shared__ float lex[32];

    const int tid = threadIdx.x;
    const int w = tid >> 6, l = tid & 63;
    const int lq = l & 15, quad = l >> 4;
    const int sw = lq & 7;                 // P-swizzle key

    // XCD-pinned remap: xcd = lin&7 owns bh {3x..3x+2}; 64 q-tiles per bh.
    const int lin  = blockIdx.x;
    const int slot = lin >> 3;                      // 0..191
    const int bh   = (lin & 7) * 3 + (slot >> 6);   // 0..23
    const int qt   = slot & 63;                     // 32-query tile
    const int b = bh / H_, h = bh % H_;
    const size_t qbase = (size_t)b * N_ * QKVC + h * HD_;
    const size_t kbase = qbase + C_;
    const size_t vbase = (size_t)bh * HD_ * N_;

    // Q B-frags (both waves: same 32 queries)
    bf16x8 qb[2][2];
#pragma unroll
    for (int nq = 0; nq < 2; ++nq)
#pragma unroll
        for (int ks = 0; ks < 2; ++ks)
            qb[nq][ks] = *(const bf16x8*)
                &qkv[qbase + (size_t)(qt * 32 + nq * 16 + lq) * QKVC
                     + ks * 32 + quad * 8];

    float lsum[2] = {0.f, 0.f};
    f32x4 oacc[4][2];
    const f32x4 z4 = {0.f, 0.f, 0.f, 0.f};
#pragma unroll
    for (int mb = 0; mb < 4; ++mb)
#pragma unroll
        for (int nq = 0; nq < 2; ++nq) oacc[mb][nq] = z4;

    // preload K frags for this wave's first key tile (kt = w)
    bf16x8 ka[4][2];
#pragma unroll
    for (int kb = 0; kb < 4; ++kb)
#pragma unroll
        for (int ks = 0; ks < 2; ++ks)
            ka[kb][ks] = *(const bf16x8*)
                &qkv[kbase + (size_t)(w * 64 + kb * 16 + lq) * QKVC
                     + ks * 32 + quad * 8];

    for (int kt2 = 0; kt2 < 16; ++kt2) {
        const int kt  = 2 * kt2 + w;
        const int ktn = (kt + 2) & 31;   // prefetch target (wraps harmlessly)
        const int kk0 = kt * 64;

        // V frags for this tile — issued early, consumed at PV below
        bf16x8 va[4][2];
#pragma unroll
        for (int mb = 0; mb < 4; ++mb)
#pragma unroll
            for (int ks = 0; ks < 2; ++ks)
                va[mb][ks] = *(const bf16x8*)
                    &vt[vbase + (size_t)(mb * 16 + lq) * N_
                        + kk0 + ks * 32 + quad * 8];

        // S^T = K.Q^T
        f32x4 sacc[4][2];
#pragma unroll
        for (int kb = 0; kb < 4; ++kb)
#pragma unroll
            for (int nq = 0; nq < 2; ++nq) sacc[kb][nq] = z4;
#pragma unroll
        for (int kb = 0; kb < 4; ++kb)
#pragma unroll
            for (int ks = 0; ks < 2; ++ks) {
#pragma unroll
                for (int nq = 0; nq < 2; ++nq)
                    sacc[kb][nq] = __builtin_amdgcn_mfma_f32_16x16x32_bf16(
                        ka[kb][ks], qb[nq][ks], sacc[kb][nq], 0, 0, 0);
            }

        // prefetch next K tile IN-PLACE (WAR on ka after S-MFMAs issued);
        // latency hides behind softmax + PV
#pragma unroll
        for (int kb = 0; kb < 4; ++kb)
#pragma unroll
            for (int ks = 0; ks < 2; ++ks)
                ka[kb][ks] = *(const bf16x8*)
                    &qkv[kbase + (size_t)(ktn * 64 + kb * 16 + lq) * QKVC
                         + ks * 32 + quad * 8];

        // static-max softmax: p = exp2(s - SMAX); no max reduce, no rescale
#pragma unroll
        for (int nq = 0; nq < 2; ++nq) {
            const int qrow = nq * 16 + lq;
#pragma unroll
            for (int kb = 0; kb < 4; ++kb) {
                float p[4];
#pragma unroll
                for (int r = 0; r < 4; ++r) p[r] = fexp2(sacc[kb][nq][r] - SMAX);
                lsum[nq] += (p[0] + p[1]) + (p[2] + p[3]);
                uint2 pkv = { pk2(p[0], p[1]), pk2(p[2], p[3]) };
                *(uint2*)&Ps[w][qrow * 64
                                + (((kb * 2 + (quad >> 1)) ^ sw) * 8)
                                + (quad & 1) * 4] = pkv;
            }
        }

        // P B-frags (same-wave LDS RAW: DS-pipe ordered, no barrier)
        bf16x8 pb[2][2];
#pragma unroll
        for (int ks = 0; ks < 2; ++ks)
#pragma unroll
            for (int nq = 0; nq < 2; ++nq)
                pb[ks][nq] = *(const bf16x8*)
                    &Ps[w][(nq * 16 + lq) * 64 + (((ks * 4 + quad) ^ sw) * 8)];

        // O^T += V^T.P^T
#pragma unroll
        for (int mb = 0; mb < 4; ++mb)
#pragma unroll
            for (int ks = 0; ks < 2; ++ks) {
#pragma unroll
                for (int nq = 0; nq < 2; ++nq)
                    oacc[mb][nq] = __builtin_amdgcn_mfma_f32_16x16x32_bf16(
                        va[mb][ks], pb[ks][nq], oacc[mb][nq], 0, 0, 0);
            }
    }

    // finish l: reduce across quad groups (all lanes get the total)
#pragma unroll
    for (int nq = 0; nq < 2; ++nq) {
        lsum[nq] += __shfl_xor(lsum[nq], 16, 64);
        lsum[nq] += __shfl_xor(lsum[nq], 32, 64);
    }

    // combine the two key-halves: wave1 -> LDS, barrier, wave0 finalizes
    if (w == 1) {
#pragma unroll
        for (int nq = 0; nq < 2; ++nq) {
#pragma unroll
            for (int mb = 0; mb < 4; ++mb) {
                const int chunk = (mb * 4 + quad) ^ lq;   // 16B-chunk swizzle
                *(float4*)&Oex[(nq * 16 + lq) * 64 + chunk * 4] =
                    *(float4*)&oacc[mb][nq];
            }
            if (quad == 0) lex[nq * 16 + lq] = lsum[nq];
        }
    }
    __syncthreads();
    if (w == 0) {
#pragma unroll
        for (int nq = 0; nq < 2; ++nq) {
            const int qrow = nq * 16 + lq;
            const float inv = 1.f / (lsum[nq] + lex[qrow]);
#pragma unroll
            for (int mb = 0; mb < 4; ++mb) {
                const int chunk = (mb * 4 + quad) ^ lq;
                const float4 oe = *(const float4*)&Oex[qrow * 64 + chunk * 4];
                const float o0 = (oacc[mb][nq][0] + oe.x) * inv;
                const float o1 = (oacc[mb][nq][1] + oe.y) * inv;
                const float o2 = (oacc[mb][nq][2] + oe.z) * inv;
                const float o3 = (oacc[mb][nq][3] + oe.w) * inv;
                uint2 ov = { pk2(o0, o1), pk2(o2, o3) };
                *(uint2*)&Ps[0][qrow * 64
                                + (((mb * 2 + (quad >> 1)) ^ sw) * 8)
                                + (quad & 1) * 4] = ov;
            }
        }
        // coalesced 16B stores of 32 q x 64 dv
#pragma unroll
        for (int pass = 0; pass < 4; ++pass) {
            const int ql = pass * 8 + (l >> 3);          // 0..31
            const int c  = l & 7;                        // dv chunk
            const bf16x8 v = *(const bf16x8*)&Ps[0][ql * 64 + ((c ^ (ql & 7)) * 8)];
            const int query = qt * 32 + ql;
            *(bf16x8*)&attnb[(size_t)(b * N_ + query) * C_ + h * HD_ + c * 8] = v;
        }
    }
}

// ---------------------------------------------------------------------------
extern "C" void kernel_launch(void* const* d_in, const int* in_sizes, int n_in,
                              void* d_out, int out_size, void* d_ws, size_t ws_size,
                              hipStream_t stream) {
    const float* x        = (const float*)d_in[0];
    const float* rope_cos = (const float*)d_in[1];
    const float* rope_sin = (const float*)d_in[2];
    const float* qkv_w    = (const float*)d_in[3];
    const float* qkv_b    = (const float*)d_in[4];
    const float* proj_w   = (const float*)d_in[5];
    const float* proj_b   = (const float*)d_in[6];
    const float* q_nw     = (const float*)d_in[7];
    const float* k_nw     = (const float*)d_in[8];
    float* out = (float*)d_out;

    // ws layout (bf16 buffers), total ~42.5 MB
    u16* xb    = (u16*)d_ws;                               // 4096x768
    u16* qwt   = xb    + (size_t)NROWS * C_;               // 2304x768 (W^T)
    u16* pwt   = qwt   + (size_t)QKVC * C_;                // 768x768  (W^T)
    u16* qkvb  = pwt   + (size_t)C_ * C_;                  // 4096x2304
    u16* vtb   = qkvb  + (size_t)NROWS * QKVC;             // (B*H*64)x2048
    u16* attnb = vtb   + (size_t)B_ * H_ * HD_ * N_;       // 4096x768

    cvt_bf16_kernel<<<dim3(NROWS * C_ / 1024), 256, 0, stream>>>(x, xb);
    wtrans_kernel<<<dim3(QKVC / 64, C_ / 64), 256, 0, stream>>>(qkv_w, qwt, C_, QKVC);
    wtrans_kernel<<<dim3(C_ / 64, C_ / 64), 256, 0, stream>>>(proj_w, pwt, C_, C_);

    gemm_tn_kernel<true><<<dim3(QKVC / 128, NROWS / 128), 256, 0, stream>>>(
        xb, qwt, qkv_b, qkvb, NROWS, QKVC, C_);

    normrope_kernel<<<dim3(NROWS * H_ / 16), 256, 0, stream>>>(
        qkvb, rope_cos, rope_sin, q_nw, k_nw);

    vtrans_kernel<<<dim3(N_ / 64, B_ * H_), 256, 0, stream>>>(qkvb, vtb);

    flash_mfma_kernel<<<dim3(64 * B_ * H_), 128, 0, stream>>>(qkvb, vtb, attnb);

    gemm_tn_kernel<false><<<dim3(C_ / 128, NROWS / 128), 256, 0, stream>>>(
        attnb, pwt, proj_b, out, NROWS, C_, C_);
}

// Round 5
// 196.620 us; speedup vs baseline: 4.4466x; 1.2219x over previous
//
#include <hip/hip_runtime.h>
#include <math.h>

#define B_    2
#define N_    2048
#define C_    768
#define H_    12
#define HD_   64
#define NROWS (B_*N_)      // 4096
#define QKVC  (3*C_)       // 2304
#define EPSV  1e-6f
#define SCALE 0.125f       // 1/sqrt(HD)
#define LOG2E 1.44269504088896f
#define SMAX  12.0f        // static softmax max: logit*log2e <= 8*1.443+eps < 12

typedef unsigned short u16;
typedef short bf16x8 __attribute__((ext_vector_type(8)));   // 8 bf16 = 4 VGPRs
typedef float f32x4  __attribute__((ext_vector_type(4)));   // MFMA C/D

__device__ __forceinline__ float b2f(u16 u) {
    unsigned v = ((unsigned)u) << 16;
    return __builtin_bit_cast(float, v);
}
__device__ __forceinline__ u16 f2b(float f) {   // RNE
    unsigned u = __builtin_bit_cast(unsigned, f);
    u += 0x7fffu + ((u >> 16) & 1u);
    return (u16)(u >> 16);
}
__device__ __forceinline__ unsigned pk2(float a, float b) {
#if __has_builtin(__builtin_amdgcn_cvt_pk_bf16_f32)
    auto r = __builtin_amdgcn_cvt_pk_bf16_f32(a, b);
    return __builtin_bit_cast(unsigned, r);
#else
    return (unsigned)f2b(a) | ((unsigned)f2b(b) << 16);
#endif
}
__device__ __forceinline__ float fexp2(float x) {
#if __has_builtin(__builtin_amdgcn_exp2f)
    return __builtin_amdgcn_exp2f(x);
#else
    return exp2f(x);
#endif
}
// async global->LDS, 16B/lane; LDS dest = wave-uniform base + lane*16
__device__ __forceinline__ void gload_lds16(const void* g, void* l) {
    __builtin_amdgcn_global_load_lds(
        (const __attribute__((address_space(1))) unsigned int*)g,
        (__attribute__((address_space(3))) unsigned int*)l, 16, 0, 0);
}

// ---------------------------------------------------------------------------
// fp32 -> bf16 elementwise (n % 1024 == 0)
// ---------------------------------------------------------------------------
__global__ __launch_bounds__(256)
void cvt_bf16_kernel(const float* __restrict__ src, u16* __restrict__ dst) {
    const int i = (blockIdx.x * 256 + threadIdx.x) * 4;
    const float4 v = *(const float4*)(src + i);
    uint2 o = { pk2(v.x, v.y), pk2(v.z, v.w) };
    *(uint2*)(dst + i) = o;
}

// ---------------------------------------------------------------------------
// W[K][N] fp32 -> Wt[N][K] bf16 (64x64 LDS tiles, both sides coalesced)
// ---------------------------------------------------------------------------
__global__ __launch_bounds__(256)
void wtrans_kernel(const float* __restrict__ W, u16* __restrict__ Wt,
                   int K, int N) {
    __shared__ float T[64][65];
    const int k0 = blockIdx.y * 64, n0 = blockIdx.x * 64;
    const int t = threadIdx.x, r = t >> 6, c = t & 63;
#pragma unroll
    for (int p = 0; p < 16; ++p) {
        const int kl = p * 4 + r;
        T[kl][c] = W[(size_t)(k0 + kl) * N + n0 + c];
    }
    __syncthreads();
#pragma unroll
    for (int p = 0; p < 16; ++p) {
        const int nl = p * 4 + r;
        Wt[(size_t)(n0 + nl) * K + k0 + c] = f2b(T[c][nl]);
    }
}

// ---------------------------------------------------------------------------
// bf16 TN GEMM: C[M][N] = A[M][K] @ Bt[N][K]^T + bias
// 128x128 tile, BK=32, 256 thr / 4 waves. LDS pitch 32 elem, 16B-chunk XOR
// swizzle (chunk ^= row&3) staged by inverting the swizzle on global addrs.
// ---------------------------------------------------------------------------
template <bool BF16OUT>
__global__ __launch_bounds__(256)
void gemm_tn_kernel(const u16* __restrict__ A, const u16* __restrict__ Bt,
                    const float* __restrict__ bias, void* __restrict__ Cout,
                    int M, int N, int K) {
    __shared__ __attribute__((aligned(16))) u16 As[128 * 32];
    __shared__ __attribute__((aligned(16))) u16 Bs[128 * 32];
    const int tid = threadIdx.x;
    const int w = tid >> 6, l = tid & 63;
    const int lq = l & 15, quad = l >> 4;
    const int mbase = blockIdx.y * 128, nbase = blockIdx.x * 128;

    f32x4 acc[4][4];
    const f32x4 z4 = {0.f, 0.f, 0.f, 0.f};
#pragma unroll
    for (int mb = 0; mb < 4; ++mb)
#pragma unroll
        for (int nb = 0; nb < 4; ++nb) acc[mb][nb] = z4;

    const int srow = (l >> 2);
    const int sdc  = (l & 3) ^ ((l >> 2) & 3);

    for (int k0 = 0; k0 < K; k0 += 32) {
#pragma unroll
        for (int cc = 0; cc < 2; ++cc) {
            const int c = 2 * w + cc;
            const int row = 16 * c + srow;
            gload_lds16(A  + (size_t)(mbase + row) * K + k0 + sdc * 8, &As[c * 512]);
            gload_lds16(Bt + (size_t)(nbase + row) * K + k0 + sdc * 8, &Bs[c * 512]);
        }
        __syncthreads();

        bf16x8 af[4], bfr[4];
#pragma unroll
        for (int mb = 0; mb < 4; ++mb)
            af[mb] = *(const bf16x8*)
                &As[((w >> 1) * 64 + mb * 16 + lq) * 32 + ((quad ^ (lq & 3)) * 8)];
#pragma unroll
        for (int nb = 0; nb < 4; ++nb)
            bfr[nb] = *(const bf16x8*)
                &Bs[((w & 1) * 64 + nb * 16 + lq) * 32 + ((quad ^ (lq & 3)) * 8)];
#pragma unroll
        for (int mb = 0; mb < 4; ++mb)
#pragma unroll
            for (int nb = 0; nb < 4; ++nb)
                acc[mb][nb] = __builtin_amdgcn_mfma_f32_16x16x32_bf16(
                    af[mb], bfr[nb], acc[mb][nb], 0, 0, 0);
        __syncthreads();
    }

#pragma unroll
    for (int nb = 0; nb < 4; ++nb) {
        const int col = nbase + (w & 1) * 64 + nb * 16 + lq;
        const float bv = bias[col];
#pragma unroll
        for (int mb = 0; mb < 4; ++mb) {
#pragma unroll
            for (int r = 0; r < 4; ++r) {
                const int row = mbase + (w >> 1) * 64 + mb * 16 + quad * 4 + r;
                const float v = acc[mb][nb][r] + bv;
                if (BF16OUT) ((u16*)Cout)[(size_t)row * N + col] = f2b(v);
                else         ((float*)Cout)[(size_t)row * N + col] = v;
            }
        }
    }
}

// ---------------------------------------------------------------------------
// RMSNorm + RoPE. 16 lanes per (row,h), ushort4 per lane.
// q (roped, *SCALE*LOG2E) -> back into qkv buffer.
// k (roped)               -> kpack, MFMA-A-fragment-packed tiles:
//   tile(bh,kt) base = (bh*32+kt)*4096 ; elem ((kb*2+ks)*64 + lane)*8 + j
//   where lane=(quad*16+m), K[key=kb*16+m][d=ks*32+quad*8+j].
// ---------------------------------------------------------------------------
__global__ __launch_bounds__(256)
void normrope_kernel(u16* __restrict__ qkv, u16* __restrict__ kpack,
                     const float* __restrict__ cosb,
                     const float* __restrict__ sinb,
                     const float* __restrict__ qw,
                     const float* __restrict__ kw) {
    const int item = blockIdx.x * 16 + (threadIdx.x >> 4); // (b*N+n)*H + h
    const int lq   = threadIdx.x & 15;
    const int h    = item % H_;
    const int row  = item / H_;        // b*N + n
    const int n    = row & (N_ - 1);
    const int b    = row >> 11;
    const size_t base = (size_t)row * QKVC + h * HD_ + lq * 4;

    const ushort4 q4 = *(const ushort4*)&qkv[base];
    const ushort4 k4 = *(const ushort4*)&qkv[base + C_];
    float qf[4], kf[4];
    qf[0] = b2f(q4.x); qf[1] = b2f(q4.y); qf[2] = b2f(q4.z); qf[3] = b2f(q4.w);
    kf[0] = b2f(k4.x); kf[1] = b2f(k4.y); kf[2] = b2f(k4.z); kf[3] = b2f(k4.w);

    float q2 = qf[0]*qf[0] + qf[1]*qf[1] + qf[2]*qf[2] + qf[3]*qf[3];
    float k2 = kf[0]*kf[0] + kf[1]*kf[1] + kf[2]*kf[2] + kf[3]*kf[3];
#pragma unroll
    for (int off = 8; off >= 1; off >>= 1) {
        q2 += __shfl_xor(q2, off, 64);
        k2 += __shfl_xor(k2, off, 64);
    }
    const float rq = rsqrtf(q2 * (1.f / 64.f) + EPSV);
    const float rk = rsqrtf(k2 * (1.f / 64.f) + EPSV);

    const float4 qwv = *(const float4*)&qw[lq * 4];
    const float4 kwv = *(const float4*)&kw[lq * 4];
    const float4 cv  = *(const float4*)&cosb[n * HD_ + lq * 4];
    const float4 sv  = *(const float4*)&sinb[n * HD_ + lq * 4];

    float qn[4], kn[4];
    qn[0] = qf[0]*rq*qwv.x; qn[1] = qf[1]*rq*qwv.y;
    qn[2] = qf[2]*rq*qwv.z; qn[3] = qf[3]*rq*qwv.w;
    kn[0] = kf[0]*rk*kwv.x; kn[1] = kf[1]*rk*kwv.y;
    kn[2] = kf[2]*rk*kwv.z; kn[3] = kf[3]*rk*kwv.w;

    const float sgn = (lq < 8) ? -1.f : 1.f;   // partner lane = lq^8 (d +/- 32)
    float qo[4], ko[4];
    const float cc[4] = {cv.x, cv.y, cv.z, cv.w};
    const float ss[4] = {sv.x, sv.y, sv.z, sv.w};
#pragma unroll
    for (int j = 0; j < 4; ++j) {
        const float qp = __shfl_xor(qn[j], 8, 64);
        const float kp = __shfl_xor(kn[j], 8, 64);
        qo[j] = (qn[j] * cc[j] + sgn * qp * ss[j]) * (SCALE * LOG2E);
        ko[j] =  kn[j] * cc[j] + sgn * kp * ss[j];
    }
    uint2 qout = { pk2(qo[0], qo[1]), pk2(qo[2], qo[3]) };
    uint2 kout = { pk2(ko[0], ko[1]), pk2(ko[2], ko[3]) };
    *(uint2*)&qkv[base] = qout;

    // k -> fragment-packed tile
    const int kt = n >> 6, kr = n & 63;
    const int kb = kr >> 4, m = kr & 15;
    const int ks = lq >> 3, quad = (lq >> 1) & 3, jj = (lq & 1) * 4;
    const size_t off = ((size_t)(b * H_ + h) * 32 + kt) * 4096
                     + (size_t)((kb * 2 + ks) * 64 + quad * 16 + m) * 8 + jj;
    *(uint2*)&kpack[off] = kout;
}

// ---------------------------------------------------------------------------
// V pack: qkv V-region -> vpack, MFMA-A-fragment-packed V^T tiles:
//   tile(bh,kt): elem ((mb*2+ks)*64 + lane)*8 + j , lane=(quad*16+m),
//   V^T[dv=mb*16+m][k=ks*32+quad*8+j] = V[key=kt*64+ks*32+quad*8+j][dv].
// One block per (kt, bh). Reads coalesced; writes 32B/thread coalesced.
// ---------------------------------------------------------------------------
__global__ __launch_bounds__(256)
void vpack_kernel(const u16* __restrict__ qkv, u16* __restrict__ vpack) {
    __shared__ u16 Tv[64][72];
    const int kt = blockIdx.x, bh = blockIdx.y;
    const int b = bh / H_, h = bh % H_;
    const int t = threadIdx.x;
    {
        const int r = t >> 2, seg = t & 3;   // row=key, 16 u16 per thread
        const u16* src = &qkv[(size_t)(b * N_ + kt * 64 + r) * QKVC
                              + 2 * C_ + h * HD_ + seg * 16];
        const uint4 v0 = *(const uint4*)src;
        const uint4 v1 = *(const uint4*)(src + 8);
        *(uint4*)&Tv[r][seg * 16]     = v0;
        *(uint4*)&Tv[r][seg * 16 + 8] = v1;
    }
    __syncthreads();
    u16 tmp[16];
#pragma unroll
    for (int g2 = 0; g2 < 2; ++g2) {
        const int g = t * 2 + g2;            // j-group 0..511
        const int mbks = g >> 6;             // (mb*2+ks)
        const int l  = g & 63;
        const int mb = mbks >> 1, ks = mbks & 1;
        const int m  = l & 15,  quad = l >> 4;
#pragma unroll
        for (int j = 0; j < 8; ++j)
            tmp[g2 * 8 + j] = Tv[ks * 32 + quad * 8 + j][mb * 16 + m];
    }
    u16* dst = &vpack[((size_t)bh * 32 + kt) * 4096 + t * 16];
    *(uint4*)dst       = *(const uint4*)&tmp[0];
    *(uint4*)(dst + 8) = *(const uint4*)&tmp[8];
}

// ---------------------------------------------------------------------------
// MFMA flash attention. Block = 2 waves over the SAME 64 queries (nq=4);
// wave w handles keys kt = 2*kt2+w. K/V loads are fragment-packed 1KB
// fully-coalesced dwordx4. Static-max softmax (SMAX) => additive partials;
// one LDS exchange + one __syncthreads combines the two key-halves.
// Grid = 768 (3 blocks/CU). XCD-pinned bh mapping keeps K/V in one L2.
// ---------------------------------------------------------------------------
__global__ __launch_bounds__(128, 2)
void flash_mfma_kernel(const u16* __restrict__ qkv,
                       const u16* __restrict__ kpack,
                       const u16* __restrict__ vpack,
                       u16* __restrict__ attnb) {
    __shared__ __attribute__((aligned(16))) u16 Ps[2][64 * 64];  // per-wave P
    __shared__ __attribute__((aligned(16))) float Oex[64 * 64];  // exchange
    __shared__ float lex[64];

    const int tid = threadIdx.x;
    const int w = tid >> 6, l = tid & 63;
    const int lq = l & 15, quad = l >> 4;
    const int sw = lq & 7;                 // P-row swizzle key

    // XCD-pinned remap: xcd = lin&7 owns bh {3x..3x+2}; 32 q-tiles per bh.
    const int lin  = blockIdx.x;
    const int slot = lin >> 3;                      // 0..95
    const int bh   = (lin & 7) * 3 + (slot >> 5);   // 0..23
    const int qt   = slot & 31;                     // 64-query tile
    const int b = bh / H_, h = bh % H_;
    const size_t qbase = (size_t)b * N_ * QKVC + h * HD_;
    const size_t tbase = (size_t)bh * 32 * 4096;    // packed-tile base for bh

    // Q B-frags (both waves: same 64 queries)
    bf16x8 qb[4][2];
#pragma unroll
    for (int nq = 0; nq < 4; ++nq)
#pragma unroll
        for (int ks = 0; ks < 2; ++ks)
            qb[nq][ks] = *(const bf16x8*)
                &qkv[qbase + (size_t)(qt * 64 + nq * 16 + lq) * QKVC
                     + ks * 32 + quad * 8];

    float lsum[4] = {0.f, 0.f, 0.f, 0.f};
    f32x4 oacc[4][4];
    const f32x4 z4 = {0.f, 0.f, 0.f, 0.f};
#pragma unroll
    for (int mb = 0; mb < 4; ++mb)
#pragma unroll
        for (int nq = 0; nq < 4; ++nq) oacc[mb][nq] = z4;

    // preload K frags for first key tile (kt = w); fully coalesced 1KB loads
    bf16x8 ka[4][2];
#pragma unroll
    for (int kb = 0; kb < 4; ++kb)
#pragma unroll
        for (int ks = 0; ks < 2; ++ks)
            ka[kb][ks] = *(const bf16x8*)
                &kpack[tbase + (size_t)w * 4096 + ((kb * 2 + ks) * 64 + l) * 8];

    for (int kt2 = 0; kt2 < 16; ++kt2) {
        const int kt  = 2 * kt2 + w;
        const int ktn = (kt + 2) & 31;       // prefetch target (wrap harmless)
        const size_t vb = tbase + (size_t)kt * 4096;
        const size_t kb_n = tbase + (size_t)ktn * 4096;

        // V frags — issued early, consumed at PV below
        bf16x8 va[4][2];
#pragma unroll
        for (int mb = 0; mb < 4; ++mb)
#pragma unroll
            for (int ks = 0; ks < 2; ++ks)
                va[mb][ks] = *(const bf16x8*)
                    &vpack[vb + ((mb * 2 + ks) * 64 + l) * 8];

        // per-kb: S-MFMAs -> exp2 -> P-write (keeps sacc lifetime short)
#pragma unroll
        for (int kb = 0; kb < 4; ++kb) {
            f32x4 sacc[4];
#pragma unroll
            for (int nq = 0; nq < 4; ++nq) sacc[nq] = z4;
#pragma unroll
            for (int ks = 0; ks < 2; ++ks)
#pragma unroll
                for (int nq = 0; nq < 4; ++nq)
                    sacc[nq] = __builtin_amdgcn_mfma_f32_16x16x32_bf16(
                        ka[kb][ks], qb[nq][ks], sacc[nq], 0, 0, 0);
#pragma unroll
            for (int nq = 0; nq < 4; ++nq) {
                float p[4];
#pragma unroll
                for (int r = 0; r < 4; ++r) p[r] = fexp2(sacc[nq][r] - SMAX);
                lsum[nq] += (p[0] + p[1]) + (p[2] + p[3]);
                uint2 pkv = { pk2(p[0], p[1]), pk2(p[2], p[3]) };
                *(uint2*)&Ps[w][(nq * 16 + lq) * 64
                                + (((kb * 2 + (quad >> 1)) ^ sw) * 8)
                                + (quad & 1) * 4] = pkv;
            }
        }

        // prefetch next K tile IN-PLACE (after all S-MFMAs consumed ka)
#pragma unroll
        for (int kb = 0; kb < 4; ++kb)
#pragma unroll
            for (int ks = 0; ks < 2; ++ks)
                ka[kb][ks] = *(const bf16x8*)
                    &kpack[kb_n + ((kb * 2 + ks) * 64 + l) * 8];

        // P B-frags (same-wave LDS RAW: DS-pipe ordered, no barrier)
        bf16x8 pb[2][4];
#pragma unroll
        for (int ks = 0; ks < 2; ++ks)
#pragma unroll
            for (int nq = 0; nq < 4; ++nq)
                pb[ks][nq] = *(const bf16x8*)
                    &Ps[w][(nq * 16 + lq) * 64 + (((ks * 4 + quad) ^ sw) * 8)];

        // O^T += V^T.P^T
#pragma unroll
        for (int mb = 0; mb < 4; ++mb)
#pragma unroll
            for (int ks = 0; ks < 2; ++ks)
#pragma unroll
                for (int nq = 0; nq < 4; ++nq)
                    oacc[mb][nq] = __builtin_amdgcn_mfma_f32_16x16x32_bf16(
                        va[mb][ks], pb[ks][nq], oacc[mb][nq], 0, 0, 0);
    }

    // finish l: reduce over quad groups
#pragma unroll
    for (int nq = 0; nq < 4; ++nq) {
        lsum[nq] += __shfl_xor(lsum[nq], 16, 64);
        lsum[nq] += __shfl_xor(lsum[nq], 32, 64);
    }

    // combine key-halves: wave1 -> LDS, barrier, wave0 finalizes
    if (w == 1) {
#pragma unroll
        for (int nq = 0; nq < 4; ++nq) {
#pragma unroll
            for (int mb = 0; mb < 4; ++mb) {
                const int chunk = (mb * 4 + quad) ^ lq;   // float4-chunk swizzle
                *(float4*)&Oex[(nq * 16 + lq) * 64 + chunk * 4] =
                    *(float4*)&oacc[mb][nq];
            }
            if (quad == 0) lex[nq * 16 + lq] = lsum[nq];
        }
    }
    __syncthreads();
    if (w == 0) {
#pragma unroll
        for (int nq = 0; nq < 4; ++nq) {
            const int qrow = nq * 16 + lq;
            const float inv = 1.f / (lsum[nq] + lex[qrow]);
#pragma unroll
            for (int mb = 0; mb < 4; ++mb) {
                const int chunk = (mb * 4 + quad) ^ lq;
                const float4 oe = *(const float4*)&Oex[qrow * 64 + chunk * 4];
                const float o0 = (oacc[mb][nq][0] + oe.x) * inv;
                const float o1 = (oacc[mb][nq][1] + oe.y) * inv;
                const float o2 = (oacc[mb][nq][2] + oe.z) * inv;
                const float o3 = (oacc[mb][nq][3] + oe.w) * inv;
                uint2 ov = { pk2(o0, o1), pk2(o2, o3) };
                *(uint2*)&Ps[0][qrow * 64
                                + (((mb * 2 + (quad >> 1)) ^ sw) * 8)
                                + (quad & 1) * 4] = ov;
            }
        }
        // coalesced 16B stores of 64 q x 64 dv
#pragma unroll
        for (int pass = 0; pass < 8; ++pass) {
            const int ql = pass * 8 + (l >> 3);          // 0..63
            const int c  = l & 7;                        // dv chunk
            const bf16x8 v = *(const bf16x8*)&Ps[0][ql * 64 + ((c ^ (ql & 7)) * 8)];
            const int query = qt * 64 + ql;
            *(bf16x8*)&attnb[(size_t)(b * N_ + query) * C_ + h * HD_ + c * 8] = v;
        }
    }
}

// ---------------------------------------------------------------------------
extern "C" void kernel_launch(void* const* d_in, const int* in_sizes, int n_in,
                              void* d_out, int out_size, void* d_ws, size_t ws_size,
                              hipStream_t stream) {
    const float* x        = (const float*)d_in[0];
    const float* rope_cos = (const float*)d_in[1];
    const float* rope_sin = (const float*)d_in[2];
    const float* qkv_w    = (const float*)d_in[3];
    const float* qkv_b    = (const float*)d_in[4];
    const float* proj_w   = (const float*)d_in[5];
    const float* proj_b   = (const float*)d_in[6];
    const float* q_nw     = (const float*)d_in[7];
    const float* k_nw     = (const float*)d_in[8];
    float* out = (float*)d_out;

    // ws layout (bf16 buffers), ~42.5 MB. kpackb ALIASES xb: xb is dead after
    // gemm1; normrope (writes kpackb) runs after gemm1 on the same stream.
    u16* xb    = (u16*)d_ws;                               // 4096x768
    u16* qwt   = xb    + (size_t)NROWS * C_;               // 2304x768 (W^T)
    u16* pwt   = qwt   + (size_t)QKVC * C_;                // 768x768  (W^T)
    u16* qkvb  = pwt   + (size_t)C_ * C_;                  // 4096x2304
    u16* vpackb= qkvb  + (size_t)NROWS * QKVC;             // 24x32x4096
    u16* attnb = vpackb+ (size_t)B_ * H_ * 32 * 4096;      // 4096x768
    u16* kpackb= xb;                                       // 24x32x4096 (alias)

    cvt_bf16_kernel<<<dim3(NROWS * C_ / 1024), 256, 0, stream>>>(x, xb);
    wtrans_kernel<<<dim3(QKVC / 64, C_ / 64), 256, 0, stream>>>(qkv_w, qwt, C_, QKVC);
    wtrans_kernel<<<dim3(C_ / 64, C_ / 64), 256, 0, stream>>>(proj_w, pwt, C_, C_);

    gemm_tn_kernel<true><<<dim3(QKVC / 128, NROWS / 128), 256, 0, stream>>>(
        xb, qwt, qkv_b, qkvb, NROWS, QKVC, C_);

    normrope_kernel<<<dim3(NROWS * H_ / 16), 256, 0, stream>>>(
        qkvb, kpackb, rope_cos, rope_sin, q_nw, k_nw);

    vpack_kernel<<<dim3(32, B_ * H_), 256, 0, stream>>>(qkvb, vpackb);

    flash_mfma_kernel<<<dim3(32 * B_ * H_ / 4 * 4), 128, 0, stream>>>(
        qkvb, kpackb, vpackb, attnb);

    gemm_tn_kernel<false><<<dim3(C_ / 128, NROWS / 128), 256, 0, stream>>>(
        attnb, pwt, proj_b, out, NROWS, C_, C_);
}